// Round 2
// baseline (242.047 us; speedup 1.0000x reference)
//
#include <hip/hip_runtime.h>
#include <cstdint>
#include <cstddef>

// Problem constants
#define NB 2
#define TT 1024
#define MMEM 1024
#define SS 2048   // M + T
#define FF 1024
#define NHD 16    // heads
#define HD 64     // head dim

typedef __attribute__((ext_vector_type(8))) short bf16x8;
typedef __attribute__((ext_vector_type(4))) float f32x4;

__device__ __forceinline__ float bf2f(short s){
  unsigned u = ((unsigned)(unsigned short)s) << 16;
  float f; __builtin_memcpy(&f, &u, 4); return f;
}
__device__ __forceinline__ short f2bf(float f){
  unsigned u; __builtin_memcpy(&u, &f, 4);
  u += 0x7fffu + ((u >> 16) & 1u);   // RNE
  return (short)(u >> 16);
}

// async global->LDS, 16 B per lane; LDS dest must be WAVE-UNIFORM base,
// HW scatters lane i to base + i*16 (m104).
typedef const __attribute__((address_space(1))) void gv_t;
typedef __attribute__((address_space(3))) void lv_t;
__device__ __forceinline__ void stage16(const void* g, void* l){
  __builtin_amdgcn_global_load_lds((gv_t*)g, (lv_t*)l, 16, 0, 0);
}

// ---------------- pack / cast kernels ----------------

// fused: kv_bf = bf16(concat(memory, x)) [B*SS,FF]; rel_bf = bf16(rel) [SS,FF]
__global__ void build_inputs(const float* __restrict__ mem, const float* __restrict__ x,
                             const float* __restrict__ rel,
                             short* __restrict__ kv, short* __restrict__ relo){
  int i = blockIdx.x * blockDim.x + threadIdx.x;  // float4 index
  const int nkv = NB * SS * FF / 4;
  const float* src; short* dst;
  if (i < nkv){
    int idx = i * 4;
    int row = idx >> 10, col = idx & 1023;
    int b = row >> 11, s = row & 2047;
    src = (s < MMEM) ? (mem + ((size_t)b*MMEM + s)*FF + col)
                     : (x   + ((size_t)b*TT + (s - MMEM))*FF + col);
    dst = kv + (size_t)i * 4;
  } else {
    int j = i - nkv;
    if (j >= SS * FF / 4) return;
    src = rel + (size_t)j * 4;
    dst = relo + (size_t)j * 4;
  }
  float4 v = *(const float4*)src;
  short4 o; o.x = f2bf(v.x); o.y = f2bf(v.y); o.z = f2bf(v.z); o.w = f2bf(v.w);
  *(short4*)dst = o;
}

// batched: out_z[c][r] = in_z[r][c], 1024x1024, f32 -> bf16
__global__ void transpose_cast5(const float* __restrict__ i0, const float* __restrict__ i1,
                                const float* __restrict__ i2, const float* __restrict__ i3,
                                const float* __restrict__ i4,
                                short* __restrict__ o0, short* __restrict__ o1,
                                short* __restrict__ o2, short* __restrict__ o3,
                                short* __restrict__ o4){
  const float* in; short* out;
  switch (blockIdx.z){
    case 0: in = i0; out = o0; break;
    case 1: in = i1; out = o1; break;
    case 2: in = i2; out = o2; break;
    case 3: in = i3; out = o3; break;
    default: in = i4; out = o4; break;
  }
  __shared__ float tile[32][33];
  int bx = blockIdx.x * 32, by = blockIdx.y * 32;
  int tx = threadIdx.x, ty = threadIdx.y;
  for (int j = ty; j < 32; j += 8)
    tile[j][tx] = in[(size_t)(by + j)*1024 + bx + tx];
  __syncthreads();
  for (int j = ty; j < 32; j += 8)
    out[(size_t)(bx + j)*1024 + by + tx] = f2bf(tile[tx][j]);
}

// ki[b, 0:M] = episode_idx; ki[b, M+t] = episode_idx[b,M-1] + cumsum(dones)[t]
// Also per 16-row q-group: valid-key interval [s_lo, s_hi).
__global__ void scan_kernel(const int* __restrict__ episode_idx, const int* __restrict__ dones,
                            int* __restrict__ ki, int2* __restrict__ ranges){
  __shared__ int kis[SS];
  __shared__ int wsum[16];
  const int b = blockIdx.x, t = threadIdx.x;
  const int lane = t & 63, wv = t >> 6;
  int v = dones[b*TT + t];
  kis[t] = episode_idx[b*MMEM + t];
  #pragma unroll
  for (int off = 1; off < 64; off <<= 1){
    int tmp = __shfl_up(v, off, 64);
    if (lane >= off) v += tmp;
  }
  if (lane == 63) wsum[wv] = v;
  __syncthreads();
  int add = 0;
  for (int w = 0; w < wv; w++) add += wsum[w];
  v += add;                              // inclusive cumsum(dones)[t]
  const int base = kis[MMEM - 1];
  const int q = base + v;
  kis[MMEM + t] = q;
  ki[b*SS + t] = kis[t];
  ki[b*SS + MMEM + t] = q;
  __syncthreads();
  if (t < 64){
    const int qlo = kis[MMEM + t*16];
    const int qhi = kis[MMEM + t*16 + 15];
    int lo = 0, hi = SS;
    while (lo < hi){ int mid = (lo + hi) >> 1; if (kis[mid] < qlo) lo = mid + 1; else hi = mid; }
    const int s_lo = lo;
    lo = 0; hi = SS;
    const int tgt = qhi + 1;
    while (lo < hi){ int mid = (lo + hi) >> 1; if (kis[mid] < tgt) lo = mid + 1; else hi = mid; }
    int s_hi = lo;                              // exclusive
    const int cap = t*16 + 15 + MMEM + 1;       // causal cap (<= SS always)
    if (s_hi > cap) s_hi = cap;
    ranges[(b << 6) + t] = make_int2(s_lo, s_hi);
  }
}

// uk[b,n,s] = sum_h u[n,h]*k[b,s,n,h];  vr[n,j] = sum_h v[n,h]*r[j,n,h]
__global__ void bias_tables(const short* __restrict__ kbf, const short* __restrict__ rbf,
                            const float* __restrict__ u, const float* __restrict__ v,
                            float* __restrict__ uk, float* __restrict__ vr){
  int i = blockIdx.x * blockDim.x + threadIdx.x;
  const short* p; const float* w; float* outp;
  if (i < NB * NHD * SS){
    int s = i & 2047, n = (i >> 11) & 15, b = i >> 15;
    p = kbf + (size_t)(b * SS + s) * 1024 + n * 64;
    w = u + n * 64;
    outp = uk + (size_t)(b * NHD + n) * SS + s;
  } else {
    int j = i - NB * NHD * SS;
    if (j >= NHD * SS) return;
    int jj = j & 2047, n = j >> 11;
    p = rbf + (size_t)jj * 1024 + n * 64;
    w = v + n * 64;
    outp = vr + (size_t)n * SS + jj;
  }
  float acc = 0.f;
  #pragma unroll
  for (int c = 0; c < 8; c++){
    bf16x8 kv8 = *(const bf16x8*)(p + c * 8);
    float4 w0 = *(const float4*)(w + c * 8);
    float4 w1 = *(const float4*)(w + c * 8 + 4);
    acc += bf2f(kv8[0])*w0.x + bf2f(kv8[1])*w0.y + bf2f(kv8[2])*w0.z + bf2f(kv8[3])*w0.w
         + bf2f(kv8[4])*w1.x + bf2f(kv8[5])*w1.y + bf2f(kv8[6])*w1.z + bf2f(kv8[7])*w1.w;
  }
  *outp = acc;
}

// ------------- 128x64 GEMM core, BK=32, explicit counted-vmcnt dbuf ---------
// R12: double-buffered at 24 KB total LDS (same as R9 -> 6 blocks/CU), with
// the m201-style explicit schedule:
//   stage(next tile, 3/thread) -> s_waitcnt vmcnt(3) -> s_barrier ->
//   ds_read + MFMA -> s_waitcnt lgkmcnt(0) -> s_barrier
// vmcnt never drains to 0 in the main loop (T4): the next tile's 3 loads stay
// in flight under compute, raising in-flight bytes/CU (R9/R11 drained to 0
// every step -> ~1 TB/s Little's-law cap).
// LDS layout per buffer: A 128x32 (8KB), B 64x32 (4KB); row = 64B = 4 chunks
// of 16B. Read-side swizzle chunk = quad ^ ((lcol>>1)&3) -> 2 lanes/bank
// (free, m136). Stage side pre-swizzles the GLOBAL chunk (m173) with
// wave-uniform LDS bases (m104). Summation order = ascending k (bit-identical
// to R9).
__device__ __forceinline__ void gemm_core_128x64(const short* __restrict__ A,
                                                 const short* __restrict__ BT,
                                                 int row0, int col0,
                                                 short* As, short* Bs,
                                                 f32x4 (&acc)[4][2]){
  const int tid = threadIdx.x;
  const int lane = tid & 63, wv = tid >> 6;
  const int lcol = lane & 15, quad = lane >> 4;
  const int wr = (wv >> 1) * 64, wc = (wv & 1) * 32;
  const int ch = (quad ^ ((lcol >> 1) & 3)) * 8;   // read-side chunk swizzle

  #pragma unroll
  for (int r = 0; r < 4; r++)
    #pragma unroll
    for (int c = 0; c < 2; c++) acc[r][c] = (f32x4){0.f, 0.f, 0.f, 0.f};

  // stage side: thread t owns LDS 16B slot t -> row rA = t>>2, slot p = t&3;
  // slot p must hold logical chunk p ^ ((rA>>1)&3)  (inverse == forward XOR)
  const int rA = tid >> 2, pA = tid & 3;
  const int lA = pA ^ ((rA >> 1) & 3);
  const short* gA = A  + (size_t)(row0 + rA) * 1024 + lA * 8;  // rows rA, rA+64
  const short* gB = BT + (size_t)(col0 + rA) * 1024 + lA * 8;  // rows 0..63
  short* dA = As + wv * 512;    // wave-uniform; HW adds lane*16B
  short* dB = Bs + wv * 512;

  // prologue: tile 0 -> buffer 0 (3 loads/thread in flight)
  stage16(gA,         dA);
  stage16(gA + 65536, dA + 2048);
  stage16(gB,         dB);

  #pragma unroll 2
  for (int k0 = 0; k0 < 1024; k0 += 32){
    const int cur = (k0 >> 5) & 1;
    if (k0 + 32 < 1024){
      const int nxt = cur ^ 1;
      // prefetch tile k0+32 into the other buffer (protected by last iter's
      // trailing lgkmcnt(0)+barrier); stays in flight under this iter's MFMA
      stage16(gA + k0 + 32,         As + nxt * 4096 + wv * 512);
      stage16(gA + 65536 + k0 + 32, As + nxt * 4096 + 2048 + wv * 512);
      stage16(gB + k0 + 32,         Bs + nxt * 2048 + wv * 512);
      asm volatile("s_waitcnt vmcnt(3)" ::: "memory");   // tile k0 landed; 3 stay in flight
    } else {
      asm volatile("s_waitcnt vmcnt(0)" ::: "memory");   // last tile
    }
    __builtin_amdgcn_s_barrier();                        // all waves' portions landed
    const short* Ab = As + cur * 4096;
    const short* Bb = Bs + cur * 2048;
    bf16x8 b0 = *(const bf16x8*)&Bb[(wc + lcol) * 32 + ch];
    bf16x8 b1 = *(const bf16x8*)&Bb[(wc + 16 + lcol) * 32 + ch];
    #pragma unroll
    for (int r = 0; r < 4; r++){
      bf16x8 a = *(const bf16x8*)&Ab[(wr + r * 16 + lcol) * 32 + ch];
      acc[r][0] = __builtin_amdgcn_mfma_f32_16x16x32_bf16(a, b0, acc[r][0], 0, 0, 0);
      acc[r][1] = __builtin_amdgcn_mfma_f32_16x16x32_bf16(a, b1, acc[r][1], 0, 0, 0);
    }
    asm volatile("s_waitcnt lgkmcnt(0)" ::: "memory");   // all LDS reads serviced
    __builtin_amdgcn_s_barrier();                        // buf[cur] safe to overwrite
  }
}

// Fused projection GEMM (128x64 tiles): blockIdx.z selects job:
//   z=0: kbf = kv @ WkT                      (4096 rows, bx<32)
//   z=1: vT  = kv @ WvT, per-head transposed (4096 rows, bx<32)
//   z=2: qb  = x @ WqT   (x in-place from kv rows [M..S); bx<16)
//   z=3: rbf = rel @ WrT (2048 rows; bx<16) + row-band skip (see below)
// K/V row-tiles entirely below the batch's minimum attended key index are
// SKIPPED (attn never reads K/V there). z=3 additionally skips rbf row-tiles
// below jrmin = min_{b,g} ((s_lo(b,g) & ~63) - 16*g + 1008): attn's R-window
// reads rows jr >= j0 = kt*64 - t16 + 1008 >= jrmin (and clamps UP to 2047,
// which is provably never skipped since jrmin <= 2032). Exact for any input.
__global__ __launch_bounds__(256) void proj_gemm(
    const short* __restrict__ kv, const short* __restrict__ relb,
    const short* __restrict__ WkT, const short* __restrict__ WvT,
    const short* __restrict__ WqT, const short* __restrict__ WrT,
    short* __restrict__ kbf, short* __restrict__ vT,
    short* __restrict__ qb, short* __restrict__ rbf,
    const int2* __restrict__ ranges){
  const int z = blockIdx.z;
  const int bx = blockIdx.x;
  const int tid = threadIdx.x;
  const short* A; const short* BT;
  int row0 = bx * 128, qbb = 0;
  __shared__ int s_jm;
  if (z == 0 || z == 1){
    const int bb = row0 >> 11;         // batch
    const int srow = row0 & 2047;      // s-index of tile start
    if (srow + 128 <= ranges[bb << 6].x) return;   // dead K/V rows
    A = kv; BT = (z == 0) ? WkT : WvT;
  }
  else if (z == 2){
    if (bx >= 16) return;
    qbb = bx >> 3;                       // batch
    A = kv + (size_t)(qbb * SS + MMEM) * 1024;   // x rows live inside kv
    row0 = (bx & 7) * 128;
    BT = WqT;
  }
  else {
    if (bx >= 16) return;
    // rbf row-band skip: compute jrmin from ranges (128 entries)
    if (tid == 0) s_jm = 0x7fffffff;
    __syncthreads();
    if (tid < 128){
      int2 e = ranges[tid];
      int jr = (e.x & ~63) - ((tid & 63) << 4) + 1008;
      atomicMin(&s_jm, jr);
    }
    __syncthreads();
    if (row0 + 128 <= s_jm) return;
    A = relb; BT = WrT;
  }
  const int col0 = blockIdx.y * 64;

  __shared__ __align__(16) short As[2 * 128 * 32];
  __shared__ __align__(16) short Bs[2 * 64 * 32];
  f32x4 acc[4][2];
  gemm_core_128x64(A, BT, row0, col0, As, Bs, acc);

  const int lane = threadIdx.x & 63, wv = threadIdx.x >> 6;
  const int lcol = lane & 15, quad = lane >> 4;
  const int wr = (wv >> 1) * 64, wc = (wv & 1) * 32;
  #pragma unroll
  for (int c = 0; c < 2; c++){
    const int cc = col0 + wc + c*16 + lcol;
    #pragma unroll
    for (int r = 0; r < 4; r++){
      #pragma unroll
      for (int ri = 0; ri < 4; ri++){
        const int rr = row0 + wr + r*16 + quad*4 + ri;
        float val = acc[r][c][ri];
        if (z == 0){
          kbf[(size_t)rr * 1024 + cc] = f2bf(val);
        } else if (z == 1){
          int b = rr >> 11, s = rr & 2047;
          vT[(size_t)(((b << 4) + (cc >> 6)) * 64 + (cc & 63)) * 2048 + s] = f2bf(val);
        } else if (z == 2){
          qb[((size_t)(qbb * TT) + rr) * 1024 + cc] = f2bf(val);
        } else {
          rbf[(size_t)rr * 1024 + cc] = f2bf(val);
        }
      }
    }
  }
}

// Output projection: out = attn @ WoT + b_out (f32 out, 2048 rows)
__global__ __launch_bounds__(256) void out_gemm(const short* __restrict__ A,
                                                const short* __restrict__ BT,
                                                const float* __restrict__ bias,
                                                float* __restrict__ C){
  const int row0 = blockIdx.x * 128, col0 = blockIdx.y * 64;
  __shared__ __align__(16) short As[2 * 128 * 32];
  __shared__ __align__(16) short Bs[2 * 64 * 32];
  f32x4 acc[4][2];
  gemm_core_128x64(A, BT, row0, col0, As, Bs, acc);

  const int lane = threadIdx.x & 63, wv = threadIdx.x >> 6;
  const int lcol = lane & 15, quad = lane >> 4;
  const int wr = (wv >> 1) * 64, wc = (wv & 1) * 32;
  #pragma unroll
  for (int c = 0; c < 2; c++){
    const int cc = col0 + wc + c*16 + lcol;
    const float bb = bias[cc];
    #pragma unroll
    for (int r = 0; r < 4; r++)
      #pragma unroll
      for (int ri = 0; ri < 4; ri++){
        const int rr = row0 + wr + r*16 + quad*4 + ri;
        C[(size_t)rr * 1024 + cc] = acc[r][c][ri] + bb;
      }
  }
}

// ---------------- flash attention: one wave per 16-row q-group --------------
// grid 2048 x 64 threads. XCD swizzle (L2 working set per XCD ~3.6 MB).
// Each wave sweeps ONLY the valid k-tile interval from ranges[].
__global__ __launch_bounds__(64) void attn_kernel(const short* __restrict__ qb,
                            const short* __restrict__ rbf,
                            const short* __restrict__ kk, const short* __restrict__ vT,
                            const int* __restrict__ ki,
                            const float* __restrict__ uk, const float* __restrict__ vr,
                            const int2* __restrict__ ranges,
                            short* __restrict__ attn_out){
  const int blk = blockIdx.x;
  const int xcd = blk & 7;
  const int idx = blk >> 3;                 // [0,256)
  const int bn  = (xcd << 2) | (idx >> 6);  // 4 (b,n) groups per XCD
  const int t16 = (idx & 63) * 16;
  const int n = bn & 15;
  const int b = bn >> 4;
  const int lane = threadIdx.x & 63;
  const int quad = lane >> 4, lcol = lane & 15;

  __shared__ __align__(16) short pb[16 * 72];

  const short* qp = qb + (size_t)(b * TT + t16 + lcol) * 1024 + n * 64 + quad * 8;
  bf16x8 aq0 = *(const bf16x8*)(qp);
  bf16x8 aq1 = *(const bf16x8*)(qp + 32);

  int trow[4], qi_r[4], sl[4];
  bool hi[4];
  #pragma unroll
  for (int r = 0; r < 4; r++){
    trow[r] = t16 + quad * 4 + r;
    qi_r[r] = ki[b * SS + MMEM + trow[r]];
    const int rt = quad * 4 + r;
    const int off = lcol + 15 - rt;
    sl[r] = quad * 16 + (off & 15);
    hi[r] = off >= 16;
  }

  float m_run[4], l_run[4];
  f32x4 o[4];
  #pragma unroll
  for (int r = 0; r < 4; r++){ m_run[r] = -1e30f; l_run[r] = 0.f; }
  #pragma unroll
  for (int c = 0; c < 4; c++) o[c] = (f32x4){0.f, 0.f, 0.f, 0.f};

  const float scale = 0.125f;
  const size_t vt_base = (size_t)((b * NHD + n) * HD);
  const short* rb_head = rbf + n * 64;
  const float* uk_row = uk + (size_t)(b * NHD + n) * SS;
  const float* vr_row = vr + (size_t)n * SS;

  const int2 rg = ranges[(b << 6) + (t16 >> 4)];
  const int kt0 = rg.x >> 6, kt1 = (rg.y - 1) >> 6;

  for (int kt = kt0; kt <= kt1; kt++){
    const int s0 = kt * 64;
    // ---- S = Q . K^T  (+ uk column bias) ----
    f32x4 sacc[4];
    float ukc[4];
    #pragma unroll
    for (int c = 0; c < 4; c++){
      const short* kp = kk + (size_t)(b * SS + s0 + 16 * c + lcol) * 1024 + n * 64 + quad * 8;
      bf16x8 b0 = *(const bf16x8*)(kp);
      bf16x8 b1 = *(const bf16x8*)(kp + 32);
      f32x4 z = (f32x4){0.f, 0.f, 0.f, 0.f};
      z = __builtin_amdgcn_mfma_f32_16x16x32_bf16(aq0, b0, z, 0, 0, 0);
      z = __builtin_amdgcn_mfma_f32_16x16x32_bf16(aq1, b1, z, 0, 0, 0);
      sacc[c] = z;
      ukc[c] = uk_row[s0 + 16 * c + lcol];
    }
    int ki_c[4];
    #pragma unroll
    for (int c = 0; c < 4; c++) ki_c[c] = ki[b * SS + s0 + 16 * c + lcol];

    // ---- D = Q . R^T (+ vr column bias) over the 80-row window ----
    const int j0 = s0 - t16 + 1008;   // >= 0 always
    f32x4 Dw[5];
    #pragma unroll
    for (int c5 = 0; c5 < 5; c5++){
      int jr = j0 + 16 * c5 + lcol;
      jr = (jr > SS - 1) ? (SS - 1) : jr;   // clamped rows are causally masked
      const short* rp = rb_head + (size_t)jr * 1024 + quad * 8;
      bf16x8 r0 = *(const bf16x8*)(rp);
      bf16x8 r1 = *(const bf16x8*)(rp + 32);
      f32x4 z = (f32x4){0.f, 0.f, 0.f, 0.f};
      z = __builtin_amdgcn_mfma_f32_16x16x32_bf16(aq0, r0, z, 0, 0, 0);
      z = __builtin_amdgcn_mfma_f32_16x16x32_bf16(aq1, r1, z, 0, 0, 0);
      const float vrj = vr_row[jr];
      #pragma unroll
      for (int r = 0; r < 4; r++) z[r] += vrj;
      Dw[c5] = z;
    }

    // ---- bias shift (Toeplitz) + mask + logits ----
    float p[4][4];
    float rowmax[4];
    #pragma unroll
    for (int r = 0; r < 4; r++) rowmax[r] = -1e30f;
    #pragma unroll
    for (int c = 0; c < 4; c++){
      const int s = s0 + 16 * c + lcol;
      #pragma unroll
      for (int r = 0; r < 4; r++){
        const float v0 = __shfl(Dw[c][r], sl[r], 64);
        const float v1 = __shfl(Dw[c + 1][r], sl[r], 64);
        const float bd = hi[r] ? v1 : v0;
        float lg = (sacc[c][r] + ukc[c] + bd) * scale;
        const bool valid = (s <= trow[r] + MMEM) && (ki_c[c] == qi_r[r]);
        lg = valid ? lg : -1e30f;
        p[c][r] = lg;
        rowmax[r] = fmaxf(rowmax[r], lg);
      }
    }
    // ---- online softmax ----
    #pragma unroll
    for (int r = 0; r < 4; r++){
      float vmx = rowmax[r];
      #pragma unroll
      for (int off = 1; off < 16; off <<= 1) vmx = fmaxf(vmx, __shfl_xor(vmx, off, 64));
      float mnew = fmaxf(m_run[r], vmx);
      float alpha = __expf(m_run[r] - mnew);
      m_run[r] = mnew;
      l_run[r] *= alpha;
      #pragma unroll
      for (int c = 0; c < 4; c++) o[c][r] *= alpha;
    }
    float psum[4] = {0.f, 0.f, 0.f, 0.f};
    #pragma unroll
    for (int c = 0; c < 4; c++)
      #pragma unroll
      for (int r = 0; r < 4; r++){
        float pv = __expf(p[c][r] - m_run[r]);
        p[c][r] = pv;
        psum[r] += pv;
      }
    #pragma unroll
    for (int r = 0; r < 4; r++){
      float vs = psum[r];
      #pragma unroll
      for (int off = 1; off < 16; off <<= 1) vs += __shfl_xor(vs, off, 64);
      l_run[r] += vs;
    }
    // ---- P: C-layout -> A-layout via LDS (wave-synchronous) ----
    #pragma unroll
    for (int c = 0; c < 4; c++)
      #pragma unroll
      for (int r = 0; r < 4; r++)
        pb[(quad * 4 + r) * 72 + 16 * c + lcol] = f2bf(p[c][r]);
    bf16x8 pa0 = *(const bf16x8*)(&pb[lcol * 72 + quad * 8]);
    bf16x8 pa1 = *(const bf16x8*)(&pb[lcol * 72 + 32 + quad * 8]);
    // ---- O += P . V ----
    #pragma unroll
    for (int c = 0; c < 4; c++){
      const short* vtp = vT + (vt_base + c * 16 + lcol) * (size_t)SS + s0 + quad * 8;
      bf16x8 bv0 = *(const bf16x8*)(vtp);
      bf16x8 bv1 = *(const bf16x8*)(vtp + 32);
      o[c] = __builtin_amdgcn_mfma_f32_16x16x32_bf16(pa0, bv0, o[c], 0, 0, 0);
      o[c] = __builtin_amdgcn_mfma_f32_16x16x32_bf16(pa1, bv1, o[c], 0, 0, 0);
    }
  }

  // ---- epilogue: normalize, store bf16 attn [B*T, N*H] ----
  #pragma unroll
  for (int r = 0; r < 4; r++){
    const float inv = 1.f / l_run[r];
    const int t = trow[r];
    #pragma unroll
    for (int c = 0; c < 4; c++)
      attn_out[(size_t)(b * TT + t) * 1024 + n * 64 + c * 16 + lcol] = f2bf(o[c][r] * inv);
  }
}

// ---------------- launcher ----------------
extern "C" void kernel_launch(void* const* d_in, const int* in_sizes, int n_in,
                              void* d_out, int out_size, void* d_ws, size_t ws_size,
                              hipStream_t stream){
  const float* x      = (const float*)d_in[0];
  const float* rel    = (const float*)d_in[1];
  const float* memory = (const float*)d_in[2];
  const int*   episode_idx = (const int*)d_in[3];
  const int*   dones  = (const int*)d_in[4];
  const float* Wq  = (const float*)d_in[5];
  const float* Wk  = (const float*)d_in[6];
  const float* Wv  = (const float*)d_in[7];
  const float* Wr  = (const float*)d_in[8];
  const float* u   = (const float*)d_in[9];
  const float* v   = (const float*)d_in[10];
  const float* Wout  = (const float*)d_in[11];
  const float* b_out = (const float*)d_in[12];
  float* out = (float*)d_out;

  char* ws = (char*)d_ws;
  size_t off = 0;
  auto alloc = [&](size_t bytes) -> char* {
    char* p = ws + off;
    off += (bytes + 255) & ~(size_t)255;
    return p;
  };
  short* kv_bf  = (short*)alloc((size_t)NB * SS * FF * 2);
  short* rel_bf = (short*)alloc((size_t)SS * FF * 2);
  short* WqT    = (short*)alloc((size_t)FF * 1024 * 2);
  short* WkT    = (short*)alloc((size_t)FF * 1024 * 2);
  short* WvT    = (short*)alloc((size_t)FF * 1024 * 2);
  short* WrT    = (short*)alloc((size_t)FF * 1024 * 2);
  short* WoT    = (short*)alloc((size_t)FF * 1024 * 2);
  short* qbuf   = (short*)alloc((size_t)NB * TT * 1024 * 2);
  short* kbf    = (short*)alloc((size_t)NB * SS * 1024 * 2);
  short* vTb    = (short*)alloc((size_t)NB * SS * 1024 * 2);
  short* rbf    = (short*)alloc((size_t)SS * 1024 * 2);
  int*   ki     = (int*)  alloc((size_t)NB * SS * 4);
  int2*  ranges = (int2*) alloc((size_t)NB * 64 * 8);
  float* ukT    = (float*)alloc((size_t)NB * NHD * SS * 4);
  float* vrT    = (float*)alloc((size_t)NHD * SS * 4);
  short* attn   = (short*)alloc((size_t)NB * TT * 1024 * 2);
  (void)ws_size; (void)in_sizes; (void)n_in; (void)out_size;

  // pack (fused kv + rel cast)
  const int n4 = NB*SS*FF/4 + SS*FF/4;
  build_inputs<<<(n4 + 255)/256, 256, 0, stream>>>(memory, x, rel, kv_bf, rel_bf);
  dim3 tb(32, 8), tg5(32, 32, 5);
  transpose_cast5<<<tg5, tb, 0, stream>>>(Wq, Wk, Wv, Wr, Wout, WqT, WkT, WvT, WrT, WoT);
  scan_kernel<<<NB, TT, 0, stream>>>(episode_idx, dones, ki, ranges);

  // fused projections, 128x64 tiles, BK=32 counted-vmcnt dbuf core (R12)
  proj_gemm<<<dim3(32, 16, 4), 256, 0, stream>>>(kv_bf, rel_bf,
                                                 WkT, WvT, WqT, WrT,
                                                 kbf, vTb, qbuf, rbf, ranges);

  // u·k / v·r column-bias tables
  bias_tables<<<(NB*NHD*SS + NHD*SS + 255)/256, 256, 0, stream>>>(kbf, rbf, u, v, ukT, vrT);

  // attention: one wave per 16-row q-group, valid-interval sweep only
  attn_kernel<<<2048, 64, 0, stream>>>(qbuf, rbf, kbf, vTb, ki, ukT, vrT, ranges, attn);

  // output projection
  out_gemm<<<dim3(16, 16), 256, 0, stream>>>(attn, WoT, b_out, out);
}

// Round 3
// 233.940 us; speedup vs baseline: 1.0347x; 1.0347x over previous
//
#include <hip/hip_runtime.h>
#include <cstdint>
#include <cstddef>

// Problem constants
#define NB 2
#define TT 1024
#define MMEM 1024
#define SS 2048   // M + T
#define FF 1024
#define NHD 16    // heads
#define HD 64     // head dim

typedef __attribute__((ext_vector_type(8))) short bf16x8;
typedef __attribute__((ext_vector_type(4))) float f32x4;

__device__ __forceinline__ float bf2f(short s){
  unsigned u = ((unsigned)(unsigned short)s) << 16;
  float f; __builtin_memcpy(&f, &u, 4); return f;
}
__device__ __forceinline__ short f2bf(float f){
  unsigned u; __builtin_memcpy(&u, &f, 4);
  u += 0x7fffu + ((u >> 16) & 1u);   // RNE
  return (short)(u >> 16);
}

// async global->LDS, 16 B per lane; LDS dest must be WAVE-UNIFORM base,
// HW scatters lane i to base + i*16 (m104).
typedef const __attribute__((address_space(1))) void gv_t;
typedef __attribute__((address_space(3))) void lv_t;
__device__ __forceinline__ void stage16(const void* g, void* l){
  __builtin_amdgcn_global_load_lds((gv_t*)g, (lv_t*)l, 16, 0, 0);
}

// ---------------- pack / cast kernels ----------------

// fused: kv_bf = bf16(concat(memory, x)) [B*SS,FF]; rel_bf = bf16(rel) [SS,FF]
__global__ void build_inputs(const float* __restrict__ mem, const float* __restrict__ x,
                             const float* __restrict__ rel,
                             short* __restrict__ kv, short* __restrict__ relo){
  int i = blockIdx.x * blockDim.x + threadIdx.x;  // float4 index
  const int nkv = NB * SS * FF / 4;
  const float* src; short* dst;
  if (i < nkv){
    int idx = i * 4;
    int row = idx >> 10, col = idx & 1023;
    int b = row >> 11, s = row & 2047;
    src = (s < MMEM) ? (mem + ((size_t)b*MMEM + s)*FF + col)
                     : (x   + ((size_t)b*TT + (s - MMEM))*FF + col);
    dst = kv + (size_t)i * 4;
  } else {
    int j = i - nkv;
    if (j >= SS * FF / 4) return;
    src = rel + (size_t)j * 4;
    dst = relo + (size_t)j * 4;
  }
  float4 v = *(const float4*)src;
  short4 o; o.x = f2bf(v.x); o.y = f2bf(v.y); o.z = f2bf(v.z); o.w = f2bf(v.w);
  *(short4*)dst = o;
}

// batched: out_z[c][r] = in_z[r][c], 1024x1024, f32 -> bf16
__global__ void transpose_cast5(const float* __restrict__ i0, const float* __restrict__ i1,
                                const float* __restrict__ i2, const float* __restrict__ i3,
                                const float* __restrict__ i4,
                                short* __restrict__ o0, short* __restrict__ o1,
                                short* __restrict__ o2, short* __restrict__ o3,
                                short* __restrict__ o4){
  const float* in; short* out;
  switch (blockIdx.z){
    case 0: in = i0; out = o0; break;
    case 1: in = i1; out = o1; break;
    case 2: in = i2; out = o2; break;
    case 3: in = i3; out = o3; break;
    default: in = i4; out = o4; break;
  }
  __shared__ float tile[32][33];
  int bx = blockIdx.x * 32, by = blockIdx.y * 32;
  int tx = threadIdx.x, ty = threadIdx.y;
  for (int j = ty; j < 32; j += 8)
    tile[j][tx] = in[(size_t)(by + j)*1024 + bx + tx];
  __syncthreads();
  for (int j = ty; j < 32; j += 8)
    out[(size_t)(bx + j)*1024 + by + tx] = f2bf(tile[tx][j]);
}

// ki[b, 0:M] = episode_idx; ki[b, M+t] = episode_idx[b,M-1] + cumsum(dones)[t]
// Also per 16-row q-group: valid-key interval [s_lo, s_hi).
__global__ void scan_kernel(const int* __restrict__ episode_idx, const int* __restrict__ dones,
                            int* __restrict__ ki, int2* __restrict__ ranges){
  __shared__ int kis[SS];
  __shared__ int wsum[16];
  const int b = blockIdx.x, t = threadIdx.x;
  const int lane = t & 63, wv = t >> 6;
  int v = dones[b*TT + t];
  kis[t] = episode_idx[b*MMEM + t];
  #pragma unroll
  for (int off = 1; off < 64; off <<= 1){
    int tmp = __shfl_up(v, off, 64);
    if (lane >= off) v += tmp;
  }
  if (lane == 63) wsum[wv] = v;
  __syncthreads();
  int add = 0;
  for (int w = 0; w < wv; w++) add += wsum[w];
  v += add;                              // inclusive cumsum(dones)[t]
  const int base = kis[MMEM - 1];
  const int q = base + v;
  kis[MMEM + t] = q;
  ki[b*SS + t] = kis[t];
  ki[b*SS + MMEM + t] = q;
  __syncthreads();
  if (t < 64){
    const int qlo = kis[MMEM + t*16];
    const int qhi = kis[MMEM + t*16 + 15];
    int lo = 0, hi = SS;
    while (lo < hi){ int mid = (lo + hi) >> 1; if (kis[mid] < qlo) lo = mid + 1; else hi = mid; }
    const int s_lo = lo;
    lo = 0; hi = SS;
    const int tgt = qhi + 1;
    while (lo < hi){ int mid = (lo + hi) >> 1; if (kis[mid] < tgt) lo = mid + 1; else hi = mid; }
    int s_hi = lo;                              // exclusive
    const int cap = t*16 + 15 + MMEM + 1;       // causal cap (<= SS always)
    if (s_hi > cap) s_hi = cap;
    ranges[(b << 6) + t] = make_int2(s_lo, s_hi);
  }
}

// uk[b,n,s] = sum_h u[n,h]*k[b,s,n,h];  vr[n,j] = sum_h v[n,h]*r[j,n,h]
__global__ void bias_tables(const short* __restrict__ kbf, const short* __restrict__ rbf,
                            const float* __restrict__ u, const float* __restrict__ v,
                            float* __restrict__ uk, float* __restrict__ vr){
  int i = blockIdx.x * blockDim.x + threadIdx.x;
  const short* p; const float* w; float* outp;
  if (i < NB * NHD * SS){
    int s = i & 2047, n = (i >> 11) & 15, b = i >> 15;
    p = kbf + (size_t)(b * SS + s) * 1024 + n * 64;
    w = u + n * 64;
    outp = uk + (size_t)(b * NHD + n) * SS + s;
  } else {
    int j = i - NB * NHD * SS;
    if (j >= NHD * SS) return;
    int jj = j & 2047, n = j >> 11;
    p = rbf + (size_t)jj * 1024 + n * 64;
    w = v + n * 64;
    outp = vr + (size_t)n * SS + jj;
  }
  float acc = 0.f;
  #pragma unroll
  for (int c = 0; c < 8; c++){
    bf16x8 kv8 = *(const bf16x8*)(p + c * 8);
    float4 w0 = *(const float4*)(w + c * 8);
    float4 w1 = *(const float4*)(w + c * 8 + 4);
    acc += bf2f(kv8[0])*w0.x + bf2f(kv8[1])*w0.y + bf2f(kv8[2])*w0.z + bf2f(kv8[3])*w0.w
         + bf2f(kv8[4])*w1.x + bf2f(kv8[5])*w1.y + bf2f(kv8[6])*w1.z + bf2f(kv8[7])*w1.w;
  }
  *outp = acc;
}

// ------------- 64x64 GEMM core, BK=64, TRIPLE-buffer depth-2 prefetch -------
// R13: stall = load_latency - prefetch_lead. R9 lead=0 (stall ~700cy/iter),
// R11 lead~350 (but 2 blocks/CU), R12 lead~200 + tiny iters. Depth-2 (tile
// i+2 staged at iter i) gives lead ~2 iters ~= latency -> stall ~0, at 48 KB
// LDS (3 bufs x (A 8KB + B 8KB)) -> still 3 blocks/CU, 12 waves/CU.
// Schedule per iter (T3/T4, counted vmcnt, never 0 mid-loop):
//   stage(tile i+2 -> buf (i+2)%3, 4 calls/thread) -> s_waitcnt vmcnt(8)
//   [tile i landed; tiles i+1,i+2 (8 calls) stay in flight] -> s_barrier ->
//   ds_read + 8 MFMA -> s_waitcnt lgkmcnt(0) -> s_barrier.
// WAR safe: buf (i+2)%3 was read at iter i-1, guarded by its trailing
// lgkmcnt(0)+barrier. vmcnt counting integrity: loop body contains ONLY
// stage16 VMEM ops; asm "memory" fences prevent the compiler hoisting any
// other global load into the counted region (R12 verified this discipline).
// XOR chunk swizzle (8x16B chunks per 128B row): reads conflict-free
// (consecutive-8-lane groups cover all 8 chunks); stage side pre-swizzles the
// GLOBAL chunk (m173) with wave-uniform LDS bases (m104).
__device__ __forceinline__ void gemm_core_64x64(const short* __restrict__ A,
                                                const short* __restrict__ BT,
                                                int row0, int col0,
                                                short* As, short* Bs,
                                                f32x4 (&acc)[2][2]){
  const int tid = threadIdx.x;
  const int lane = tid & 63, wv = tid >> 6;
  const int lcol = lane & 15, quad = lane >> 4;
  const int wr = (wv >> 1) * 32, wc = (wv & 1) * 32;
  const int sw = lcol & 7;
  const int ch0 = (quad ^ sw) * 8;
  const int ch1 = ((4 + quad) ^ sw) * 8;

  #pragma unroll
  for (int r = 0; r < 2; r++)
    #pragma unroll
    for (int c = 0; c < 2; c++) acc[r][c] = (f32x4){0.f, 0.f, 0.f, 0.f};

  // stage side: call j covers LDS slots j*256+tid -> row r = j*32 + (tid>>3),
  // phys chunk p = tid&7 must hold logical chunk p ^ (r&7)
  const int rs = tid >> 3, ps = tid & 7;
  const int ls = ps ^ (rs & 7);
  const short* gA = A  + (size_t)(row0 + rs) * 1024 + ls * 8;
  const short* gB = BT + (size_t)(col0 + rs) * 1024 + ls * 8;

  auto STAGE = [&](int k0, int bi){
    short* a = As + bi * 4096 + wv * 512;   // wave-uniform; HW adds lane*16B
    short* b = Bs + bi * 4096 + wv * 512;
    stage16(gA + k0,         a);
    stage16(gA + 32768 + k0, a + 2048);     // rows +32
    stage16(gB + k0,         b);
    stage16(gB + 32768 + k0, b + 2048);
  };

  // prologue: tiles 0,1 in flight (8 loads/thread outstanding)
  STAGE(0, 0);
  STAGE(64, 1);

  #pragma unroll 1
  for (int i = 0; i < 16; ++i){
    const int cur = i - (i / 3) * 3;        // i % 3
    if (i <= 13){
      const int nb = (i + 2) - ((i + 2) / 3) * 3;
      STAGE((i + 2) << 6, nb);
      asm volatile("s_waitcnt vmcnt(8)" ::: "memory");  // tile i landed; 8 in flight
    } else if (i == 14){
      asm volatile("s_waitcnt vmcnt(4)" ::: "memory");
    } else {
      asm volatile("s_waitcnt vmcnt(0)" ::: "memory");
    }
    __builtin_amdgcn_s_barrier();           // all waves' portions of tile i landed
    const short* Ab = As + cur * 4096;
    const short* Bb = Bs + cur * 4096;
    bf16x8 b00 = *(const bf16x8*)&Bb[(wc + lcol) * 64 + ch0];
    bf16x8 b01 = *(const bf16x8*)&Bb[(wc + lcol) * 64 + ch1];
    bf16x8 b10 = *(const bf16x8*)&Bb[(wc + 16 + lcol) * 64 + ch0];
    bf16x8 b11 = *(const bf16x8*)&Bb[(wc + 16 + lcol) * 64 + ch1];
    #pragma unroll
    for (int r = 0; r < 2; r++){
      bf16x8 a0 = *(const bf16x8*)&Ab[(wr + r * 16 + lcol) * 64 + ch0];
      bf16x8 a1 = *(const bf16x8*)&Ab[(wr + r * 16 + lcol) * 64 + ch1];
      acc[r][0] = __builtin_amdgcn_mfma_f32_16x16x32_bf16(a0, b00, acc[r][0], 0, 0, 0);
      acc[r][0] = __builtin_amdgcn_mfma_f32_16x16x32_bf16(a1, b01, acc[r][0], 0, 0, 0);
      acc[r][1] = __builtin_amdgcn_mfma_f32_16x16x32_bf16(a0, b10, acc[r][1], 0, 0, 0);
      acc[r][1] = __builtin_amdgcn_mfma_f32_16x16x32_bf16(a1, b11, acc[r][1], 0, 0, 0);
    }
    asm volatile("s_waitcnt lgkmcnt(0)" ::: "memory");   // all LDS reads serviced
    __builtin_amdgcn_s_barrier();           // buf[cur] safe to overwrite
  }
}

// Fused projection GEMM (64x64 tiles): blockIdx.z selects job:
//   z=0: kbf = kv @ WkT                      (4096 rows, bx<64)
//   z=1: vT  = kv @ WvT, per-head transposed (4096 rows, bx<64)
//   z=2: qb  = x @ WqT   (x in-place from kv rows [M..S); bx<32)
//   z=3: rbf = rel @ WrT (2048 rows; bx<32) + row-band skip
// K/V row-tiles entirely below the batch's minimum attended key index are
// SKIPPED (attn reads start at (s_lo&~63); skipped tiles end below that).
// z=3 skips rbf row-tiles below jrmin = min_{b,g}((s_lo&~63) - 16g + 1008).
__global__ __launch_bounds__(256) void proj_gemm(
    const short* __restrict__ kv, const short* __restrict__ relb,
    const short* __restrict__ WkT, const short* __restrict__ WvT,
    const short* __restrict__ WqT, const short* __restrict__ WrT,
    short* __restrict__ kbf, short* __restrict__ vT,
    short* __restrict__ qb, short* __restrict__ rbf,
    const int2* __restrict__ ranges){
  const int z = blockIdx.z;
  const int bx = blockIdx.x;
  const int tid = threadIdx.x;
  const short* A; const short* BT;
  int row0 = bx * 64, qbb = 0;
  __shared__ int s_jm;
  if (z == 0 || z == 1){
    const int bb = row0 >> 11;         // batch
    const int srow = row0 & 2047;      // s-index of tile start
    if (srow + 64 <= ranges[bb << 6].x) return;   // dead K/V rows
    A = kv; BT = (z == 0) ? WkT : WvT;
  }
  else if (z == 2){
    if (bx >= 32) return;
    qbb = bx >> 4;                       // batch
    A = kv + (size_t)(qbb * SS + MMEM) * 1024;   // x rows live inside kv
    row0 = (bx & 15) * 64;
    BT = WqT;
  }
  else {
    if (bx >= 32) return;
    if (tid == 0) s_jm = 0x7fffffff;
    __syncthreads();
    if (tid < 128){
      int2 e = ranges[tid];
      int jr = (e.x & ~63) - ((tid & 63) << 4) + 1008;
      atomicMin(&s_jm, jr);
    }
    __syncthreads();
    if (row0 + 64 <= s_jm) return;
    A = relb; BT = WrT;
  }
  const int col0 = blockIdx.y * 64;

  __shared__ __align__(16) short As[3 * 64 * 64];
  __shared__ __align__(16) short Bs[3 * 64 * 64];
  f32x4 acc[2][2];
  gemm_core_64x64(A, BT, row0, col0, As, Bs, acc);

  const int lane = threadIdx.x & 63, wv = threadIdx.x >> 6;
  const int lcol = lane & 15, quad = lane >> 4;
  const int wr = (wv >> 1) * 32, wc = (wv & 1) * 32;
  #pragma unroll
  for (int c = 0; c < 2; c++){
    const int cc = col0 + wc + c*16 + lcol;
    #pragma unroll
    for (int r = 0; r < 2; r++){
      #pragma unroll
      for (int ri = 0; ri < 4; ri++){
        const int rr = row0 + wr + r*16 + quad*4 + ri;
        float val = acc[r][c][ri];
        if (z == 0){
          kbf[(size_t)rr * 1024 + cc] = f2bf(val);
        } else if (z == 1){
          int b = rr >> 11, s = rr & 2047;
          vT[(size_t)(((b << 4) + (cc >> 6)) * 64 + (cc & 63)) * 2048 + s] = f2bf(val);
        } else if (z == 2){
          qb[((size_t)(qbb * TT) + rr) * 1024 + cc] = f2bf(val);
        } else {
          rbf[(size_t)rr * 1024 + cc] = f2bf(val);
        }
      }
    }
  }
}

// Output projection: out = attn @ WoT + b_out (f32 out, 2048 rows)
__global__ __launch_bounds__(256) void out_gemm(const short* __restrict__ A,
                                                const short* __restrict__ BT,
                                                const float* __restrict__ bias,
                                                float* __restrict__ C){
  const int row0 = blockIdx.x * 64, col0 = blockIdx.y * 64;
  __shared__ __align__(16) short As[3 * 64 * 64];
  __shared__ __align__(16) short Bs[3 * 64 * 64];
  f32x4 acc[2][2];
  gemm_core_64x64(A, BT, row0, col0, As, Bs, acc);

  const int lane = threadIdx.x & 63, wv = threadIdx.x >> 6;
  const int lcol = lane & 15, quad = lane >> 4;
  const int wr = (wv >> 1) * 32, wc = (wv & 1) * 32;
  #pragma unroll
  for (int c = 0; c < 2; c++){
    const int cc = col0 + wc + c*16 + lcol;
    const float bb = bias[cc];
    #pragma unroll
    for (int r = 0; r < 2; r++)
      #pragma unroll
      for (int ri = 0; ri < 4; ri++){
        const int rr = row0 + wr + r*16 + quad*4 + ri;
        C[(size_t)rr * 1024 + cc] = acc[r][c][ri] + bb;
      }
  }
}

// ---------------- flash attention: one wave per 16-row q-group --------------
// grid 2048 x 64 threads. XCD swizzle (L2 working set per XCD ~3.6 MB).
// Each wave sweeps ONLY the valid k-tile interval from ranges[].
__global__ __launch_bounds__(64) void attn_kernel(const short* __restrict__ qb,
                            const short* __restrict__ rbf,
                            const short* __restrict__ kk, const short* __restrict__ vT,
                            const int* __restrict__ ki,
                            const float* __restrict__ uk, const float* __restrict__ vr,
                            const int2* __restrict__ ranges,
                            short* __restrict__ attn_out){
  const int blk = blockIdx.x;
  const int xcd = blk & 7;
  const int idx = blk >> 3;                 // [0,256)
  const int bn  = (xcd << 2) | (idx >> 6);  // 4 (b,n) groups per XCD
  const int t16 = (idx & 63) * 16;
  const int n = bn & 15;
  const int b = bn >> 4;
  const int lane = threadIdx.x & 63;
  const int quad = lane >> 4, lcol = lane & 15;

  __shared__ __align__(16) short pb[16 * 72];

  const short* qp = qb + (size_t)(b * TT + t16 + lcol) * 1024 + n * 64 + quad * 8;
  bf16x8 aq0 = *(const bf16x8*)(qp);
  bf16x8 aq1 = *(const bf16x8*)(qp + 32);

  int trow[4], qi_r[4], sl[4];
  bool hi[4];
  #pragma unroll
  for (int r = 0; r < 4; r++){
    trow[r] = t16 + quad * 4 + r;
    qi_r[r] = ki[b * SS + MMEM + trow[r]];
    const int rt = quad * 4 + r;
    const int off = lcol + 15 - rt;
    sl[r] = quad * 16 + (off & 15);
    hi[r] = off >= 16;
  }

  float m_run[4], l_run[4];
  f32x4 o[4];
  #pragma unroll
  for (int r = 0; r < 4; r++){ m_run[r] = -1e30f; l_run[r] = 0.f; }
  #pragma unroll
  for (int c = 0; c < 4; c++) o[c] = (f32x4){0.f, 0.f, 0.f, 0.f};

  const float scale = 0.125f;
  const size_t vt_base = (size_t)((b * NHD + n) * HD);
  const short* rb_head = rbf + n * 64;
  const float* uk_row = uk + (size_t)(b * NHD + n) * SS;
  const float* vr_row = vr + (size_t)n * SS;

  const int2 rg = ranges[(b << 6) + (t16 >> 4)];
  const int kt0 = rg.x >> 6, kt1 = (rg.y - 1) >> 6;

  for (int kt = kt0; kt <= kt1; kt++){
    const int s0 = kt * 64;
    // ---- S = Q . K^T  (+ uk column bias) ----
    f32x4 sacc[4];
    float ukc[4];
    #pragma unroll
    for (int c = 0; c < 4; c++){
      const short* kp = kk + (size_t)(b * SS + s0 + 16 * c + lcol) * 1024 + n * 64 + quad * 8;
      bf16x8 b0 = *(const bf16x8*)(kp);
      bf16x8 b1 = *(const bf16x8*)(kp + 32);
      f32x4 z = (f32x4){0.f, 0.f, 0.f, 0.f};
      z = __builtin_amdgcn_mfma_f32_16x16x32_bf16(aq0, b0, z, 0, 0, 0);
      z = __builtin_amdgcn_mfma_f32_16x16x32_bf16(aq1, b1, z, 0, 0, 0);
      sacc[c] = z;
      ukc[c] = uk_row[s0 + 16 * c + lcol];
    }
    int ki_c[4];
    #pragma unroll
    for (int c = 0; c < 4; c++) ki_c[c] = ki[b * SS + s0 + 16 * c + lcol];

    // ---- D = Q . R^T (+ vr column bias) over the 80-row window ----
    const int j0 = s0 - t16 + 1008;   // >= 0 always
    f32x4 Dw[5];
    #pragma unroll
    for (int c5 = 0; c5 < 5; c5++){
      int jr = j0 + 16 * c5 + lcol;
      jr = (jr > SS - 1) ? (SS - 1) : jr;   // clamped rows are causally masked
      const short* rp = rb_head + (size_t)jr * 1024 + quad * 8;
      bf16x8 r0 = *(const bf16x8*)(rp);
      bf16x8 r1 = *(const bf16x8*)(rp + 32);
      f32x4 z = (f32x4){0.f, 0.f, 0.f, 0.f};
      z = __builtin_amdgcn_mfma_f32_16x16x32_bf16(aq0, r0, z, 0, 0, 0);
      z = __builtin_amdgcn_mfma_f32_16x16x32_bf16(aq1, r1, z, 0, 0, 0);
      const float vrj = vr_row[jr];
      #pragma unroll
      for (int r = 0; r < 4; r++) z[r] += vrj;
      Dw[c5] = z;
    }

    // ---- bias shift (Toeplitz) + mask + logits ----
    float p[4][4];
    float rowmax[4];
    #pragma unroll
    for (int r = 0; r < 4; r++) rowmax[r] = -1e30f;
    #pragma unroll
    for (int c = 0; c < 4; c++){
      const int s = s0 + 16 * c + lcol;
      #pragma unroll
      for (int r = 0; r < 4; r++){
        const float v0 = __shfl(Dw[c][r], sl[r], 64);
        const float v1 = __shfl(Dw[c + 1][r], sl[r], 64);
        const float bd = hi[r] ? v1 : v0;
        float lg = (sacc[c][r] + ukc[c] + bd) * scale;
        const bool valid = (s <= trow[r] + MMEM) && (ki_c[c] == qi_r[r]);
        lg = valid ? lg : -1e30f;
        p[c][r] = lg;
        rowmax[r] = fmaxf(rowmax[r], lg);
      }
    }
    // ---- online softmax ----
    #pragma unroll
    for (int r = 0; r < 4; r++){
      float vmx = rowmax[r];
      #pragma unroll
      for (int off = 1; off < 16; off <<= 1) vmx = fmaxf(vmx, __shfl_xor(vmx, off, 64));
      float mnew = fmaxf(m_run[r], vmx);
      float alpha = __expf(m_run[r] - mnew);
      m_run[r] = mnew;
      l_run[r] *= alpha;
      #pragma unroll
      for (int c = 0; c < 4; c++) o[c][r] *= alpha;
    }
    float psum[4] = {0.f, 0.f, 0.f, 0.f};
    #pragma unroll
    for (int c = 0; c < 4; c++)
      #pragma unroll
      for (int r = 0; r < 4; r++){
        float pv = __expf(p[c][r] - m_run[r]);
        p[c][r] = pv;
        psum[r] += pv;
      }
    #pragma unroll
    for (int r = 0; r < 4; r++){
      float vs = psum[r];
      #pragma unroll
      for (int off = 1; off < 16; off <<= 1) vs += __shfl_xor(vs, off, 64);
      l_run[r] += vs;
    }
    // ---- P: C-layout -> A-layout via LDS (wave-synchronous) ----
    #pragma unroll
    for (int c = 0; c < 4; c++)
      #pragma unroll
      for (int r = 0; r < 4; r++)
        pb[(quad * 4 + r) * 72 + 16 * c + lcol] = f2bf(p[c][r]);
    bf16x8 pa0 = *(const bf16x8*)(&pb[lcol * 72 + quad * 8]);
    bf16x8 pa1 = *(const bf16x8*)(&pb[lcol * 72 + 32 + quad * 8]);
    // ---- O += P . V ----
    #pragma unroll
    for (int c = 0; c < 4; c++){
      const short* vtp = vT + (vt_base + c * 16 + lcol) * (size_t)SS + s0 + quad * 8;
      bf16x8 bv0 = *(const bf16x8*)(vtp);
      bf16x8 bv1 = *(const bf16x8*)(vtp + 32);
      o[c] = __builtin_amdgcn_mfma_f32_16x16x32_bf16(pa0, bv0, o[c], 0, 0, 0);
      o[c] = __builtin_amdgcn_mfma_f32_16x16x32_bf16(pa1, bv1, o[c], 0, 0, 0);
    }
  }

  // ---- epilogue: normalize, store bf16 attn [B*T, N*H] ----
  #pragma unroll
  for (int r = 0; r < 4; r++){
    const float inv = 1.f / l_run[r];
    const int t = trow[r];
    #pragma unroll
    for (int c = 0; c < 4; c++)
      attn_out[(size_t)(b * TT + t) * 1024 + n * 64 + c * 16 + lcol] = f2bf(o[c][r] * inv);
  }
}

// ---------------- launcher ----------------
extern "C" void kernel_launch(void* const* d_in, const int* in_sizes, int n_in,
                              void* d_out, int out_size, void* d_ws, size_t ws_size,
                              hipStream_t stream){
  const float* x      = (const float*)d_in[0];
  const float* rel    = (const float*)d_in[1];
  const float* memory = (const float*)d_in[2];
  const int*   episode_idx = (const int*)d_in[3];
  const int*   dones  = (const int*)d_in[4];
  const float* Wq  = (const float*)d_in[5];
  const float* Wk  = (const float*)d_in[6];
  const float* Wv  = (const float*)d_in[7];
  const float* Wr  = (const float*)d_in[8];
  const float* u   = (const float*)d_in[9];
  const float* v   = (const float*)d_in[10];
  const float* Wout  = (const float*)d_in[11];
  const float* b_out = (const float*)d_in[12];
  float* out = (float*)d_out;

  char* ws = (char*)d_ws;
  size_t off = 0;
  auto alloc = [&](size_t bytes) -> char* {
    char* p = ws + off;
    off += (bytes + 255) & ~(size_t)255;
    return p;
  };
  short* kv_bf  = (short*)alloc((size_t)NB * SS * FF * 2);
  short* rel_bf = (short*)alloc((size_t)SS * FF * 2);
  short* WqT    = (short*)alloc((size_t)FF * 1024 * 2);
  short* WkT    = (short*)alloc((size_t)FF * 1024 * 2);
  short* WvT    = (short*)alloc((size_t)FF * 1024 * 2);
  short* WrT    = (short*)alloc((size_t)FF * 1024 * 2);
  short* WoT    = (short*)alloc((size_t)FF * 1024 * 2);
  short* qbuf   = (short*)alloc((size_t)NB * TT * 1024 * 2);
  short* kbf    = (short*)alloc((size_t)NB * SS * 1024 * 2);
  short* vTb    = (short*)alloc((size_t)NB * SS * 1024 * 2);
  short* rbf    = (short*)alloc((size_t)SS * 1024 * 2);
  int*   ki     = (int*)  alloc((size_t)NB * SS * 4);
  int2*  ranges = (int2*) alloc((size_t)NB * 64 * 8);
  float* ukT    = (float*)alloc((size_t)NB * NHD * SS * 4);
  float* vrT    = (float*)alloc((size_t)NHD * SS * 4);
  short* attn   = (short*)alloc((size_t)NB * TT * 1024 * 2);
  (void)ws_size; (void)in_sizes; (void)n_in; (void)out_size;

  // pack (fused kv + rel cast)
  const int n4 = NB*SS*FF/4 + SS*FF/4;
  build_inputs<<<(n4 + 255)/256, 256, 0, stream>>>(memory, x, rel, kv_bf, rel_bf);
  dim3 tb(32, 8), tg5(32, 32, 5);
  transpose_cast5<<<tg5, tb, 0, stream>>>(Wq, Wk, Wv, Wr, Wout, WqT, WkT, WvT, WrT, WoT);
  scan_kernel<<<NB, TT, 0, stream>>>(episode_idx, dones, ki, ranges);

  // fused projections, 64x64 tiles, BK=64 triple-buffer depth-2 core (R13)
  proj_gemm<<<dim3(64, 16, 4), 256, 0, stream>>>(kv_bf, rel_bf,
                                                 WkT, WvT, WqT, WrT,
                                                 kbf, vTb, qbuf, rbf, ranges);

  // u·k / v·r column-bias tables
  bias_tables<<<(NB*NHD*SS + NHD*SS + 255)/256, 256, 0, stream>>>(kbf, rbf, u, v, ukT, vrT);

  // attention: one wave per 16-row q-group, valid-interval sweep only
  attn_kernel<<<2048, 64, 0, stream>>>(qbuf, rbf, kbf, vTb, ki, ukT, vrT, ranges, attn);

  // output projection
  out_gemm<<<dim3(32, 16), 256, 0, stream>>>(attn, WoT, b_out, out);
}

// Round 4
// 217.252 us; speedup vs baseline: 1.1141x; 1.0768x over previous
//
#include <hip/hip_runtime.h>
#include <cstdint>
#include <cstddef>

// Problem constants
#define NB 2
#define TT 1024
#define MMEM 1024
#define SS 2048   // M + T
#define FF 1024
#define NHD 16    // heads
#define HD 64     // head dim

typedef __attribute__((ext_vector_type(8))) short bf16x8;
typedef __attribute__((ext_vector_type(4))) float f32x4;

__device__ __forceinline__ float bf2f(short s){
  unsigned u = ((unsigned)(unsigned short)s) << 16;
  float f; __builtin_memcpy(&f, &u, 4); return f;
}
__device__ __forceinline__ short f2bf(float f){
  unsigned u; __builtin_memcpy(&u, &f, 4);
  u += 0x7fffu + ((u >> 16) & 1u);   // RNE
  return (short)(u >> 16);
}

// async global->LDS, 16 B per lane; LDS dest must be WAVE-UNIFORM base,
// HW scatters lane i to base + i*16 (m104).
typedef const __attribute__((address_space(1))) void gv_t;
typedef __attribute__((address_space(3))) void lv_t;
__device__ __forceinline__ void stage16(const void* g, void* l){
  __builtin_amdgcn_global_load_lds((gv_t*)g, (lv_t*)l, 16, 0, 0);
}

// LDS byte offset of a generic pointer into __shared__ (HK lds_byte pattern):
// shared aperture is 4GB-aligned, so low 32 bits of the as3 address are the
// LDS byte offset usable as the ds_read vaddr.
typedef __attribute__((address_space(3))) const short ls3_t;
__device__ __forceinline__ unsigned lds_off(const short* p){
  return (unsigned)(size_t)(ls3_t*)p;
}

// inline-asm ds_read_b128. CRITICAL: no "memory" clobber — the compiler must
// NOT see an LDS-read dependency on the outstanding global_load_lds queue, or
// it inserts its own s_waitcnt vmcnt(0) (the R11-R13 silent drain). Ordering
// vs staging is done manually: counted vmcnt + s_barrier + sched_barrier(0)
// fences, and lgkmcnt(0)+sched_barrier(0) before the consuming MFMAs (rule #18).
template<int OFF>
__device__ __forceinline__ bf16x8 ds_read16(unsigned a){
  bf16x8 d;
  if constexpr (OFF == 0)
    asm volatile("ds_read_b128 %0, %1" : "=v"(d) : "v"(a));
  else
    asm volatile("ds_read_b128 %0, %1 offset:2048" : "=v"(d) : "v"(a));
  return d;
}

// ---------------- pack / cast kernels ----------------

// fused: kv_bf = bf16(concat(memory, x)) [B*SS,FF]; rel_bf = bf16(rel) [SS,FF]
__global__ void build_inputs(const float* __restrict__ mem, const float* __restrict__ x,
                             const float* __restrict__ rel,
                             short* __restrict__ kv, short* __restrict__ relo){
  int i = blockIdx.x * blockDim.x + threadIdx.x;  // float4 index
  const int nkv = NB * SS * FF / 4;
  const float* src; short* dst;
  if (i < nkv){
    int idx = i * 4;
    int row = idx >> 10, col = idx & 1023;
    int b = row >> 11, s = row & 2047;
    src = (s < MMEM) ? (mem + ((size_t)b*MMEM + s)*FF + col)
                     : (x   + ((size_t)b*TT + (s - MMEM))*FF + col);
    dst = kv + (size_t)i * 4;
  } else {
    int j = i - nkv;
    if (j >= SS * FF / 4) return;
    src = rel + (size_t)j * 4;
    dst = relo + (size_t)j * 4;
  }
  float4 v = *(const float4*)src;
  short4 o; o.x = f2bf(v.x); o.y = f2bf(v.y); o.z = f2bf(v.z); o.w = f2bf(v.w);
  *(short4*)dst = o;
}

// batched: out_z[c][r] = in_z[r][c], 1024x1024, f32 -> bf16
__global__ void transpose_cast5(const float* __restrict__ i0, const float* __restrict__ i1,
                                const float* __restrict__ i2, const float* __restrict__ i3,
                                const float* __restrict__ i4,
                                short* __restrict__ o0, short* __restrict__ o1,
                                short* __restrict__ o2, short* __restrict__ o3,
                                short* __restrict__ o4){
  const float* in; short* out;
  switch (blockIdx.z){
    case 0: in = i0; out = o0; break;
    case 1: in = i1; out = o1; break;
    case 2: in = i2; out = o2; break;
    case 3: in = i3; out = o3; break;
    default: in = i4; out = o4; break;
  }
  __shared__ float tile[32][33];
  int bx = blockIdx.x * 32, by = blockIdx.y * 32;
  int tx = threadIdx.x, ty = threadIdx.y;
  for (int j = ty; j < 32; j += 8)
    tile[j][tx] = in[(size_t)(by + j)*1024 + bx + tx];
  __syncthreads();
  for (int j = ty; j < 32; j += 8)
    out[(size_t)(bx + j)*1024 + by + tx] = f2bf(tile[tx][j]);
}

// ki[b, 0:M] = episode_idx; ki[b, M+t] = episode_idx[b,M-1] + cumsum(dones)[t]
// Also per 16-row q-group: valid-key interval [s_lo, s_hi).
__global__ void scan_kernel(const int* __restrict__ episode_idx, const int* __restrict__ dones,
                            int* __restrict__ ki, int2* __restrict__ ranges){
  __shared__ int kis[SS];
  __shared__ int wsum[16];
  const int b = blockIdx.x, t = threadIdx.x;
  const int lane = t & 63, wv = t >> 6;
  int v = dones[b*TT + t];
  kis[t] = episode_idx[b*MMEM + t];
  #pragma unroll
  for (int off = 1; off < 64; off <<= 1){
    int tmp = __shfl_up(v, off, 64);
    if (lane >= off) v += tmp;
  }
  if (lane == 63) wsum[wv] = v;
  __syncthreads();
  int add = 0;
  for (int w = 0; w < wv; w++) add += wsum[w];
  v += add;                              // inclusive cumsum(dones)[t]
  const int base = kis[MMEM - 1];
  const int q = base + v;
  kis[MMEM + t] = q;
  ki[b*SS + t] = kis[t];
  ki[b*SS + MMEM + t] = q;
  __syncthreads();
  if (t < 64){
    const int qlo = kis[MMEM + t*16];
    const int qhi = kis[MMEM + t*16 + 15];
    int lo = 0, hi = SS;
    while (lo < hi){ int mid = (lo + hi) >> 1; if (kis[mid] < qlo) lo = mid + 1; else hi = mid; }
    const int s_lo = lo;
    lo = 0; hi = SS;
    const int tgt = qhi + 1;
    while (lo < hi){ int mid = (lo + hi) >> 1; if (kis[mid] < tgt) lo = mid + 1; else hi = mid; }
    int s_hi = lo;                              // exclusive
    const int cap = t*16 + 15 + MMEM + 1;       // causal cap (<= SS always)
    if (s_hi > cap) s_hi = cap;
    ranges[(b << 6) + t] = make_int2(s_lo, s_hi);
  }
}

// uk[b,n,s] = sum_h u[n,h]*k[b,s,n,h];  vr[n,j] = sum_h v[n,h]*r[j,n,h]
__global__ void bias_tables(const short* __restrict__ kbf, const short* __restrict__ rbf,
                            const float* __restrict__ u, const float* __restrict__ v,
                            float* __restrict__ uk, float* __restrict__ vr){
  int i = blockIdx.x * blockDim.x + threadIdx.x;
  const short* p; const float* w; float* outp;
  if (i < NB * NHD * SS){
    int s = i & 2047, n = (i >> 11) & 15, b = i >> 15;
    p = kbf + (size_t)(b * SS + s) * 1024 + n * 64;
    w = u + n * 64;
    outp = uk + (size_t)(b * NHD + n) * SS + s;
  } else {
    int j = i - NB * NHD * SS;
    if (j >= NHD * SS) return;
    int jj = j & 2047, n = j >> 11;
    p = rbf + (size_t)jj * 1024 + n * 64;
    w = v + n * 64;
    outp = vr + (size_t)n * SS + jj;
  }
  float acc = 0.f;
  #pragma unroll
  for (int c = 0; c < 8; c++){
    bf16x8 kv8 = *(const bf16x8*)(p + c * 8);
    float4 w0 = *(const float4*)(w + c * 8);
    float4 w1 = *(const float4*)(w + c * 8 + 4);
    acc += bf2f(kv8[0])*w0.x + bf2f(kv8[1])*w0.y + bf2f(kv8[2])*w0.z + bf2f(kv8[3])*w0.w
         + bf2f(kv8[4])*w1.x + bf2f(kv8[5])*w1.y + bf2f(kv8[6])*w1.z + bf2f(kv8[7])*w1.w;
  }
  *outp = acc;
}

// ------------- 64x64 GEMM core, BK=64, triple-buffer depth-2, ASM ds_read ---
// R14: same geometry/schedule as R13 (verified correct), but the 8 LDS reads
// are inline-asm ds_read_b128. R11-R13 all failed the same way (BW <= 1 TB/s,
// never rose): the compiler, seeing C++ ds_reads dependent on global_load_lds
// LDS writes, inserted its OWN s_waitcnt vmcnt(0) before them — silently
// draining the counted-vmcnt pipeline every iteration. asm ds_reads carry no
// compiler-visible LDS dependency, so the only waits are ours:
//   STAGE(i+2) -> vmcnt(8) [tiles i+1,i+2 stay in flight] -> s_barrier ->
//   sched_barrier(0) -> 8x asm ds_read -> lgkmcnt(0) -> sched_barrier(0)
//   [rule #18] -> 8 MFMA -> sched_barrier(0) -> s_barrier.
// WAR safe: buf (i+2)%3 was read in iter i-1; those reads completed at iter
// i-1's pre-MFMA lgkmcnt(0), before its tail barrier, which precedes this
// iter's STAGE (cross-wave by barrier). Summation order ascending k ->
// bit-identical to R13/R9.
__device__ __forceinline__ void gemm_core_64x64(const short* __restrict__ A,
                                                const short* __restrict__ BT,
                                                int row0, int col0,
                                                short* As, short* Bs,
                                                f32x4 (&acc)[2][2]){
  const int tid = threadIdx.x;
  const int lane = tid & 63, wv = tid >> 6;
  const int lcol = lane & 15, quad = lane >> 4;
  const int wr = (wv >> 1) * 32, wc = (wv & 1) * 32;
  const int sw = lcol & 7;
  const int ch0 = (quad ^ sw) * 8;
  const int ch1 = ((4 + quad) ^ sw) * 8;

  #pragma unroll
  for (int r = 0; r < 2; r++)
    #pragma unroll
    for (int c = 0; c < 2; c++) acc[r][c] = (f32x4){0.f, 0.f, 0.f, 0.f};

  // stage side: call j covers LDS slots j*256+tid -> row r = j*32 + (tid>>3),
  // phys chunk p = tid&7 must hold logical chunk p ^ (r&7)
  const int rs = tid >> 3, ps = tid & 7;
  const int ls = ps ^ (rs & 7);
  const short* gA = A  + (size_t)(row0 + rs) * 1024 + ls * 8;
  const short* gB = BT + (size_t)(col0 + rs) * 1024 + ls * 8;

  auto STAGE = [&](int k0, int bi){
    short* a = As + bi * 4096 + wv * 512;   // wave-uniform; HW adds lane*16B
    short* b = Bs + bi * 4096 + wv * 512;
    stage16(gA + k0,         a);
    stage16(gA + 32768 + k0, a + 2048);     // rows +32
    stage16(gB + k0,         b);
    stage16(gB + 32768 + k0, b + 2048);
  };

  // per-lane LDS read byte addresses (buffer 0); +cur*8192 per iter.
  // Read row (wr|wc + {0,16} + lcol): row&7 == lcol&7 == sw, so phys chunk
  // ch0/ch1 holds logical chunk quad / 4+quad -> k-slices [q*8) and [32+q*8).
  const unsigned oa0 = lds_off(As) + (unsigned)(((wr + lcol) * 64 + ch0) * 2);
  const unsigned oa1 = lds_off(As) + (unsigned)(((wr + lcol) * 64 + ch1) * 2);
  const unsigned ob0 = lds_off(Bs) + (unsigned)(((wc + lcol) * 64 + ch0) * 2);
  const unsigned ob1 = lds_off(Bs) + (unsigned)(((wc + lcol) * 64 + ch1) * 2);

  // prologue: tiles 0,1 in flight (8 loads/thread outstanding)
  STAGE(0, 0);
  STAGE(64, 1);

  #pragma unroll 1
  for (int i = 0; i < 16; ++i){
    const int cur = i - (i / 3) * 3;        // i % 3
    if (i <= 13){
      const int nb = (i + 2) - ((i + 2) / 3) * 3;
      STAGE((i + 2) << 6, nb);
      asm volatile("s_waitcnt vmcnt(8)" ::: "memory");  // tile i landed; 8 in flight
    } else if (i == 14){
      asm volatile("s_waitcnt vmcnt(4)" ::: "memory");
    } else {
      asm volatile("s_waitcnt vmcnt(0)" ::: "memory");
    }
    __builtin_amdgcn_s_barrier();           // all waves' portions of tile i landed
    __builtin_amdgcn_sched_barrier(0);      // nothing crosses into the read region
    const unsigned bo = (unsigned)(cur * 8192);
    bf16x8 b00 = ds_read16<0>(ob0 + bo);
    bf16x8 b01 = ds_read16<0>(ob1 + bo);
    bf16x8 b10 = ds_read16<2048>(ob0 + bo);   // row +16
    bf16x8 b11 = ds_read16<2048>(ob1 + bo);
    bf16x8 a00 = ds_read16<0>(oa0 + bo);
    bf16x8 a01 = ds_read16<0>(oa1 + bo);
    bf16x8 a10 = ds_read16<2048>(oa0 + bo);   // row +16
    bf16x8 a11 = ds_read16<2048>(oa1 + bo);
    asm volatile("s_waitcnt lgkmcnt(0)" ::: "memory");  // ds_reads complete
    __builtin_amdgcn_sched_barrier(0);      // rule #18: pin MFMAs after the wait
    acc[0][0] = __builtin_amdgcn_mfma_f32_16x16x32_bf16(a00, b00, acc[0][0], 0, 0, 0);
    acc[0][0] = __builtin_amdgcn_mfma_f32_16x16x32_bf16(a01, b01, acc[0][0], 0, 0, 0);
    acc[0][1] = __builtin_amdgcn_mfma_f32_16x16x32_bf16(a00, b10, acc[0][1], 0, 0, 0);
    acc[0][1] = __builtin_amdgcn_mfma_f32_16x16x32_bf16(a01, b11, acc[0][1], 0, 0, 0);
    acc[1][0] = __builtin_amdgcn_mfma_f32_16x16x32_bf16(a10, b00, acc[1][0], 0, 0, 0);
    acc[1][0] = __builtin_amdgcn_mfma_f32_16x16x32_bf16(a11, b01, acc[1][0], 0, 0, 0);
    acc[1][1] = __builtin_amdgcn_mfma_f32_16x16x32_bf16(a10, b10, acc[1][1], 0, 0, 0);
    acc[1][1] = __builtin_amdgcn_mfma_f32_16x16x32_bf16(a11, b11, acc[1][1], 0, 0, 0);
    __builtin_amdgcn_sched_barrier(0);      // keep MFMAs inside this iteration
    __builtin_amdgcn_s_barrier();           // buf[cur] safe to overwrite
  }
}

// Fused projection GEMM (64x64 tiles): blockIdx.z selects job:
//   z=0: kbf = kv @ WkT                      (4096 rows, bx<64)
//   z=1: vT  = kv @ WvT, per-head transposed (4096 rows, bx<64)
//   z=2: qb  = x @ WqT   (x in-place from kv rows [M..S); bx<32)
//   z=3: rbf = rel @ WrT (2048 rows; bx<32) + row-band skip
// K/V row-tiles entirely below the batch's minimum attended key index are
// SKIPPED (attn reads start at (s_lo&~63); skipped tiles end below that).
// z=3 skips rbf row-tiles below jrmin = min_{b,g}((s_lo&~63) - 16g + 1008).
__global__ __launch_bounds__(256) void proj_gemm(
    const short* __restrict__ kv, const short* __restrict__ relb,
    const short* __restrict__ WkT, const short* __restrict__ WvT,
    const short* __restrict__ WqT, const short* __restrict__ WrT,
    short* __restrict__ kbf, short* __restrict__ vT,
    short* __restrict__ qb, short* __restrict__ rbf,
    const int2* __restrict__ ranges){
  const int z = blockIdx.z;
  const int bx = blockIdx.x;
  const int tid = threadIdx.x;
  const short* A; const short* BT;
  int row0 = bx * 64, qbb = 0;
  __shared__ int s_jm;
  if (z == 0 || z == 1){
    const int bb = row0 >> 11;         // batch
    const int srow = row0 & 2047;      // s-index of tile start
    if (srow + 64 <= ranges[bb << 6].x) return;   // dead K/V rows
    A = kv; BT = (z == 0) ? WkT : WvT;
  }
  else if (z == 2){
    if (bx >= 32) return;
    qbb = bx >> 4;                       // batch
    A = kv + (size_t)(qbb * SS + MMEM) * 1024;   // x rows live inside kv
    row0 = (bx & 15) * 64;
    BT = WqT;
  }
  else {
    if (bx >= 32) return;
    if (tid == 0) s_jm = 0x7fffffff;
    __syncthreads();
    if (tid < 128){
      int2 e = ranges[tid];
      int jr = (e.x & ~63) - ((tid & 63) << 4) + 1008;
      atomicMin(&s_jm, jr);
    }
    __syncthreads();
    if (row0 + 64 <= s_jm) return;
    A = relb; BT = WrT;
  }
  const int col0 = blockIdx.y * 64;

  __shared__ __align__(16) short As[3 * 64 * 64];
  __shared__ __align__(16) short Bs[3 * 64 * 64];
  f32x4 acc[2][2];
  gemm_core_64x64(A, BT, row0, col0, As, Bs, acc);

  const int lane = threadIdx.x & 63, wv = threadIdx.x >> 6;
  const int lcol = lane & 15, quad = lane >> 4;
  const int wr = (wv >> 1) * 32, wc = (wv & 1) * 32;
  #pragma unroll
  for (int c = 0; c < 2; c++){
    const int cc = col0 + wc + c*16 + lcol;
    #pragma unroll
    for (int r = 0; r < 2; r++){
      #pragma unroll
      for (int ri = 0; ri < 4; ri++){
        const int rr = row0 + wr + r*16 + quad*4 + ri;
        float val = acc[r][c][ri];
        if (z == 0){
          kbf[(size_t)rr * 1024 + cc] = f2bf(val);
        } else if (z == 1){
          int b = rr >> 11, s = rr & 2047;
          vT[(size_t)(((b << 4) + (cc >> 6)) * 64 + (cc & 63)) * 2048 + s] = f2bf(val);
        } else if (z == 2){
          qb[((size_t)(qbb * TT) + rr) * 1024 + cc] = f2bf(val);
        } else {
          rbf[(size_t)rr * 1024 + cc] = f2bf(val);
        }
      }
    }
  }
}

// Output projection: out = attn @ WoT + b_out (f32 out, 2048 rows)
__global__ __launch_bounds__(256) void out_gemm(const short* __restrict__ A,
                                                const short* __restrict__ BT,
                                                const float* __restrict__ bias,
                                                float* __restrict__ C){
  const int row0 = blockIdx.x * 64, col0 = blockIdx.y * 64;
  __shared__ __align__(16) short As[3 * 64 * 64];
  __shared__ __align__(16) short Bs[3 * 64 * 64];
  f32x4 acc[2][2];
  gemm_core_64x64(A, BT, row0, col0, As, Bs, acc);

  const int lane = threadIdx.x & 63, wv = threadIdx.x >> 6;
  const int lcol = lane & 15, quad = lane >> 4;
  const int wr = (wv >> 1) * 32, wc = (wv & 1) * 32;
  #pragma unroll
  for (int c = 0; c < 2; c++){
    const int cc = col0 + wc + c*16 + lcol;
    const float bb = bias[cc];
    #pragma unroll
    for (int r = 0; r < 2; r++)
      #pragma unroll
      for (int ri = 0; ri < 4; ri++){
        const int rr = row0 + wr + r*16 + quad*4 + ri;
        C[(size_t)rr * 1024 + cc] = acc[r][c][ri] + bb;
      }
  }
}

// ---------------- flash attention: one wave per 16-row q-group --------------
// grid 2048 x 64 threads. XCD swizzle (L2 working set per XCD ~3.6 MB).
// Each wave sweeps ONLY the valid k-tile interval from ranges[].
__global__ __launch_bounds__(64) void attn_kernel(const short* __restrict__ qb,
                            const short* __restrict__ rbf,
                            const short* __restrict__ kk, const short* __restrict__ vT,
                            const int* __restrict__ ki,
                            const float* __restrict__ uk, const float* __restrict__ vr,
                            const int2* __restrict__ ranges,
                            short* __restrict__ attn_out){
  const int blk = blockIdx.x;
  const int xcd = blk & 7;
  const int idx = blk >> 3;                 // [0,256)
  const int bn  = (xcd << 2) | (idx >> 6);  // 4 (b,n) groups per XCD
  const int t16 = (idx & 63) * 16;
  const int n = bn & 15;
  const int b = bn >> 4;
  const int lane = threadIdx.x & 63;
  const int quad = lane >> 4, lcol = lane & 15;

  __shared__ __align__(16) short pb[16 * 72];

  const short* qp = qb + (size_t)(b * TT + t16 + lcol) * 1024 + n * 64 + quad * 8;
  bf16x8 aq0 = *(const bf16x8*)(qp);
  bf16x8 aq1 = *(const bf16x8*)(qp + 32);

  int trow[4], qi_r[4], sl[4];
  bool hi[4];
  #pragma unroll
  for (int r = 0; r < 4; r++){
    trow[r] = t16 + quad * 4 + r;
    qi_r[r] = ki[b * SS + MMEM + trow[r]];
    const int rt = quad * 4 + r;
    const int off = lcol + 15 - rt;
    sl[r] = quad * 16 + (off & 15);
    hi[r] = off >= 16;
  }

  float m_run[4], l_run[4];
  f32x4 o[4];
  #pragma unroll
  for (int r = 0; r < 4; r++){ m_run[r] = -1e30f; l_run[r] = 0.f; }
  #pragma unroll
  for (int c = 0; c < 4; c++) o[c] = (f32x4){0.f, 0.f, 0.f, 0.f};

  const float scale = 0.125f;
  const size_t vt_base = (size_t)((b * NHD + n) * HD);
  const short* rb_head = rbf + n * 64;
  const float* uk_row = uk + (size_t)(b * NHD + n) * SS;
  const float* vr_row = vr + (size_t)n * SS;

  const int2 rg = ranges[(b << 6) + (t16 >> 4)];
  const int kt0 = rg.x >> 6, kt1 = (rg.y - 1) >> 6;

  for (int kt = kt0; kt <= kt1; kt++){
    const int s0 = kt * 64;
    // ---- S = Q . K^T  (+ uk column bias) ----
    f32x4 sacc[4];
    float ukc[4];
    #pragma unroll
    for (int c = 0; c < 4; c++){
      const short* kp = kk + (size_t)(b * SS + s0 + 16 * c + lcol) * 1024 + n * 64 + quad * 8;
      bf16x8 b0 = *(const bf16x8*)(kp);
      bf16x8 b1 = *(const bf16x8*)(kp + 32);
      f32x4 z = (f32x4){0.f, 0.f, 0.f, 0.f};
      z = __builtin_amdgcn_mfma_f32_16x16x32_bf16(aq0, b0, z, 0, 0, 0);
      z = __builtin_amdgcn_mfma_f32_16x16x32_bf16(aq1, b1, z, 0, 0, 0);
      sacc[c] = z;
      ukc[c] = uk_row[s0 + 16 * c + lcol];
    }
    int ki_c[4];
    #pragma unroll
    for (int c = 0; c < 4; c++) ki_c[c] = ki[b * SS + s0 + 16 * c + lcol];

    // ---- D = Q . R^T (+ vr column bias) over the 80-row window ----
    const int j0 = s0 - t16 + 1008;   // >= 0 always
    f32x4 Dw[5];
    #pragma unroll
    for (int c5 = 0; c5 < 5; c5++){
      int jr = j0 + 16 * c5 + lcol;
      jr = (jr > SS - 1) ? (SS - 1) : jr;   // clamped rows are causally masked
      const short* rp = rb_head + (size_t)jr * 1024 + quad * 8;
      bf16x8 r0 = *(const bf16x8*)(rp);
      bf16x8 r1 = *(const bf16x8*)(rp + 32);
      f32x4 z = (f32x4){0.f, 0.f, 0.f, 0.f};
      z = __builtin_amdgcn_mfma_f32_16x16x32_bf16(aq0, r0, z, 0, 0, 0);
      z = __builtin_amdgcn_mfma_f32_16x16x32_bf16(aq1, r1, z, 0, 0, 0);
      const float vrj = vr_row[jr];
      #pragma unroll
      for (int r = 0; r < 4; r++) z[r] += vrj;
      Dw[c5] = z;
    }

    // ---- bias shift (Toeplitz) + mask + logits ----
    float p[4][4];
    float rowmax[4];
    #pragma unroll
    for (int r = 0; r < 4; r++) rowmax[r] = -1e30f;
    #pragma unroll
    for (int c = 0; c < 4; c++){
      const int s = s0 + 16 * c + lcol;
      #pragma unroll
      for (int r = 0; r < 4; r++){
        const float v0 = __shfl(Dw[c][r], sl[r], 64);
        const float v1 = __shfl(Dw[c + 1][r], sl[r], 64);
        const float bd = hi[r] ? v1 : v0;
        float lg = (sacc[c][r] + ukc[c] + bd) * scale;
        const bool valid = (s <= trow[r] + MMEM) && (ki_c[c] == qi_r[r]);
        lg = valid ? lg : -1e30f;
        p[c][r] = lg;
        rowmax[r] = fmaxf(rowmax[r], lg);
      }
    }
    // ---- online softmax ----
    #pragma unroll
    for (int r = 0; r < 4; r++){
      float vmx = rowmax[r];
      #pragma unroll
      for (int off = 1; off < 16; off <<= 1) vmx = fmaxf(vmx, __shfl_xor(vmx, off, 64));
      float mnew = fmaxf(m_run[r], vmx);
      float alpha = __expf(m_run[r] - mnew);
      m_run[r] = mnew;
      l_run[r] *= alpha;
      #pragma unroll
      for (int c = 0; c < 4; c++) o[c][r] *= alpha;
    }
    float psum[4] = {0.f, 0.f, 0.f, 0.f};
    #pragma unroll
    for (int c = 0; c < 4; c++)
      #pragma unroll
      for (int r = 0; r < 4; r++){
        float pv = __expf(p[c][r] - m_run[r]);
        p[c][r] = pv;
        psum[r] += pv;
      }
    #pragma unroll
    for (int r = 0; r < 4; r++){
      float vs = psum[r];
      #pragma unroll
      for (int off = 1; off < 16; off <<= 1) vs += __shfl_xor(vs, off, 64);
      l_run[r] += vs;
    }
    // ---- P: C-layout -> A-layout via LDS (wave-synchronous) ----
    #pragma unroll
    for (int c = 0; c < 4; c++)
      #pragma unroll
      for (int r = 0; r < 4; r++)
        pb[(quad * 4 + r) * 72 + 16 * c + lcol] = f2bf(p[c][r]);
    bf16x8 pa0 = *(const bf16x8*)(&pb[lcol * 72 + quad * 8]);
    bf16x8 pa1 = *(const bf16x8*)(&pb[lcol * 72 + 32 + quad * 8]);
    // ---- O += P . V ----
    #pragma unroll
    for (int c = 0; c < 4; c++){
      const short* vtp = vT + (vt_base + c * 16 + lcol) * (size_t)SS + s0 + quad * 8;
      bf16x8 bv0 = *(const bf16x8*)(vtp);
      bf16x8 bv1 = *(const bf16x8*)(vtp + 32);
      o[c] = __builtin_amdgcn_mfma_f32_16x16x32_bf16(pa0, bv0, o[c], 0, 0, 0);
      o[c] = __builtin_amdgcn_mfma_f32_16x16x32_bf16(pa1, bv1, o[c], 0, 0, 0);
    }
  }

  // ---- epilogue: normalize, store bf16 attn [B*T, N*H] ----
  #pragma unroll
  for (int r = 0; r < 4; r++){
    const float inv = 1.f / l_run[r];
    const int t = trow[r];
    #pragma unroll
    for (int c = 0; c < 4; c++)
      attn_out[(size_t)(b * TT + t) * 1024 + n * 64 + c * 16 + lcol] = f2bf(o[c][r] * inv);
  }
}

// ---------------- launcher ----------------
extern "C" void kernel_launch(void* const* d_in, const int* in_sizes, int n_in,
                              void* d_out, int out_size, void* d_ws, size_t ws_size,
                              hipStream_t stream){
  const float* x      = (const float*)d_in[0];
  const float* rel    = (const float*)d_in[1];
  const float* memory = (const float*)d_in[2];
  const int*   episode_idx = (const int*)d_in[3];
  const int*   dones  = (const int*)d_in[4];
  const float* Wq  = (const float*)d_in[5];
  const float* Wk  = (const float*)d_in[6];
  const float* Wv  = (const float*)d_in[7];
  const float* Wr  = (const float*)d_in[8];
  const float* u   = (const float*)d_in[9];
  const float* v   = (const float*)d_in[10];
  const float* Wout  = (const float*)d_in[11];
  const float* b_out = (const float*)d_in[12];
  float* out = (float*)d_out;

  char* ws = (char*)d_ws;
  size_t off = 0;
  auto alloc = [&](size_t bytes) -> char* {
    char* p = ws + off;
    off += (bytes + 255) & ~(size_t)255;
    return p;
  };
  short* kv_bf  = (short*)alloc((size_t)NB * SS * FF * 2);
  short* rel_bf = (short*)alloc((size_t)SS * FF * 2);
  short* WqT    = (short*)alloc((size_t)FF * 1024 * 2);
  short* WkT    = (short*)alloc((size_t)FF * 1024 * 2);
  short* WvT    = (short*)alloc((size_t)FF * 1024 * 2);
  short* WrT    = (short*)alloc((size_t)FF * 1024 * 2);
  short* WoT    = (short*)alloc((size_t)FF * 1024 * 2);
  short* qbuf   = (short*)alloc((size_t)NB * TT * 1024 * 2);
  short* kbf    = (short*)alloc((size_t)NB * SS * 1024 * 2);
  short* vTb    = (short*)alloc((size_t)NB * SS * 1024 * 2);
  short* rbf    = (short*)alloc((size_t)SS * 1024 * 2);
  int*   ki     = (int*)  alloc((size_t)NB * SS * 4);
  int2*  ranges = (int2*) alloc((size_t)NB * 64 * 8);
  float* ukT    = (float*)alloc((size_t)NB * NHD * SS * 4);
  float* vrT    = (float*)alloc((size_t)NHD * SS * 4);
  short* attn   = (short*)alloc((size_t)NB * TT * 1024 * 2);
  (void)ws_size; (void)in_sizes; (void)n_in; (void)out_size;

  // pack (fused kv + rel cast)
  const int n4 = NB*SS*FF/4 + SS*FF/4;
  build_inputs<<<(n4 + 255)/256, 256, 0, stream>>>(memory, x, rel, kv_bf, rel_bf);
  dim3 tb(32, 8), tg5(32, 32, 5);
  transpose_cast5<<<tg5, tb, 0, stream>>>(Wq, Wk, Wv, Wr, Wout, WqT, WkT, WvT, WrT, WoT);
  scan_kernel<<<NB, TT, 0, stream>>>(episode_idx, dones, ki, ranges);

  // fused projections, 64x64 tiles, triple-buffer depth-2 + asm ds_read (R14)
  proj_gemm<<<dim3(64, 16, 4), 256, 0, stream>>>(kv_bf, rel_bf,
                                                 WkT, WvT, WqT, WrT,
                                                 kbf, vTb, qbuf, rbf, ranges);

  // u·k / v·r column-bias tables
  bias_tables<<<(NB*NHD*SS + NHD*SS + 255)/256, 256, 0, stream>>>(kbf, rbf, u, v, ukT, vrT);

  // attention: one wave per 16-row q-group, valid-interval sweep only
  attn_kernel<<<2048, 64, 0, stream>>>(qbuf, rbf, kbf, vTb, ki, ukT, vrT, ranges, attn);

  // output projection
  out_gemm<<<dim3(32, 16), 256, 0, stream>>>(attn, WoT, b_out, out);
}

// Round 5
// 202.189 us; speedup vs baseline: 1.1971x; 1.0745x over previous
//
#include <hip/hip_runtime.h>
#include <cstdint>
#include <cstddef>

// Problem constants
#define NB 2
#define TT 1024
#define MMEM 1024
#define SS 2048   // M + T
#define FF 1024
#define NHD 16    // heads
#define HD 64    // head dim

typedef __attribute__((ext_vector_type(8))) short bf16x8;
typedef __attribute__((ext_vector_type(4))) float f32x4;

__device__ __forceinline__ float bf2f(short s){
  unsigned u = ((unsigned)(unsigned short)s) << 16;
  float f; __builtin_memcpy(&f, &u, 4); return f;
}
__device__ __forceinline__ short f2bf(float f){
  unsigned u; __builtin_memcpy(&u, &f, 4);
  u += 0x7fffu + ((u >> 16) & 1u);   // RNE
  return (short)(u >> 16);
}

// async global->LDS, 16 B per lane; LDS dest must be WAVE-UNIFORM base,
// HW scatters lane i to base + i*16 (m104).
typedef const __attribute__((address_space(1))) void gv_t;
typedef __attribute__((address_space(3))) void lv_t;
__device__ __forceinline__ void stage16(const void* g, void* l){
  __builtin_amdgcn_global_load_lds((gv_t*)g, (lv_t*)l, 16, 0, 0);
}

// LDS byte offset of a generic pointer into __shared__ (HK lds_byte pattern).
typedef __attribute__((address_space(3))) const short ls3_t;
__device__ __forceinline__ unsigned lds_off(const short* p){
  return (unsigned)(size_t)(ls3_t*)p;
}

// inline-asm ds_read_b128. No "memory" clobber — the compiler must NOT see an
// LDS-read dependency on the outstanding global_load_lds queue, or it inserts
// its own s_waitcnt vmcnt(0) (the R11-R13 silent drain). Ordering is manual:
// counted vmcnt + s_barrier + sched_barrier(0), lgkmcnt(0)+sched_barrier(0)
// before the consuming MFMAs (rule #18).
template<int OFF>
__device__ __forceinline__ bf16x8 ds_read16(unsigned a){
  bf16x8 d;
  if constexpr (OFF == 0)
    asm volatile("ds_read_b128 %0, %1" : "=v"(d) : "v"(a));
  else
    asm volatile("ds_read_b128 %0, %1 offset:2048" : "=v"(d) : "v"(a));
  return d;
}

// ---------------- merged prep kernel ----------------
// R15: build_inputs + transpose_cast5 + scan fused into ONE launch (they are
// mutually independent; all feed proj). Saves 2 serialized launch gaps and
// overlaps their memory streams. Block ranges:
//   [0, 6144)          : kv/rel pack (f32 -> bf16), flat float4 indexing
//   [6144, 6144+5120)  : 5x 1024x1024 transpose-cast (f32 -> bf16)
//   [11264, 11266)     : per-batch scan (256-thread version, integer-exact)
#define NKVB 6144
#define NTRB 5120

__global__ __launch_bounds__(256) void prep_kernel(
    const float* __restrict__ mem, const float* __restrict__ x,
    const float* __restrict__ rel,
    const int* __restrict__ episode_idx, const int* __restrict__ dones,
    const float* __restrict__ w0, const float* __restrict__ w1,
    const float* __restrict__ w2, const float* __restrict__ w3,
    const float* __restrict__ w4,
    short* __restrict__ kv, short* __restrict__ relo,
    short* __restrict__ o0, short* __restrict__ o1,
    short* __restrict__ o2, short* __restrict__ o3, short* __restrict__ o4,
    int* __restrict__ ki, int2* __restrict__ ranges){
  const int blk = blockIdx.x;
  const int tid = threadIdx.x;

  if (blk < NKVB){
    // ---- pack: kv_bf = bf16(concat(memory, x)); rel_bf = bf16(rel) ----
    int i = blk * 256 + tid;  // float4 index
    const int nkv = NB * SS * FF / 4;
    const float* src; short* dst;
    if (i < nkv){
      int idx = i * 4;
      int row = idx >> 10, col = idx & 1023;
      int b = row >> 11, s = row & 2047;
      src = (s < MMEM) ? (mem + ((size_t)b*MMEM + s)*FF + col)
                       : (x   + ((size_t)b*TT + (s - MMEM))*FF + col);
      dst = kv + (size_t)i * 4;
    } else {
      int j = i - nkv;
      src = rel + (size_t)j * 4;
      dst = relo + (size_t)j * 4;
    }
    float4 v = *(const float4*)src;
    short4 o; o.x = f2bf(v.x); o.y = f2bf(v.y); o.z = f2bf(v.z); o.w = f2bf(v.w);
    *(short4*)dst = o;
    return;
  }

  if (blk < NKVB + NTRB){
    // ---- transpose-cast: out_z[c][r] = bf16(in_z[r][c]), 1024x1024 ----
    const int j = blk - NKVB;
    const int z5 = j >> 10;
    const int rem = j & 1023;
    const int by5 = rem >> 5, bx5 = rem & 31;
    const float* in; short* out;
    switch (z5){
      case 0: in = w0; out = o0; break;
      case 1: in = w1; out = o1; break;
      case 2: in = w2; out = o2; break;
      case 3: in = w3; out = o3; break;
      default: in = w4; out = o4; break;
    }
    __shared__ float tile[32][33];
    const int bx = bx5 * 32, by = by5 * 32;
    const int tx = tid & 31, ty = tid >> 5;
    for (int jj = ty; jj < 32; jj += 8)
      tile[jj][tx] = in[(size_t)(by + jj)*1024 + bx + tx];
    __syncthreads();
    for (int jj = ty; jj < 32; jj += 8)
      out[(size_t)(bx + jj)*1024 + by + tx] = f2bf(tile[tx][jj]);
    return;
  }

  // ---- scan (256 threads): ki + per-16-row-group valid-key ranges ----
  {
    const int b = blk - (NKVB + NTRB);
    __shared__ int kis[SS];
    __shared__ int wsum[4];
    const int t = tid;
    const int lane = t & 63, wv = t >> 6;
    #pragma unroll
    for (int j = 0; j < 4; j++) kis[t*4 + j] = episode_idx[b*MMEM + t*4 + j];
    int d[4]; int s = 0;
    #pragma unroll
    for (int j = 0; j < 4; j++){ d[j] = dones[b*TT + t*4 + j]; s += d[j]; }
    int v = s;
    #pragma unroll
    for (int off = 1; off < 64; off <<= 1){
      int tmp = __shfl_up(v, off, 64);
      if (lane >= off) v += tmp;
    }
    if (lane == 63) wsum[wv] = v;
    __syncthreads();                      // kis[0:1024] + wsum visible
    int add = 0;
    for (int w = 0; w < wv; w++) add += wsum[w];
    const int base = kis[MMEM - 1];
    int run = add + v - s;                // exclusive prefix before this thread
    #pragma unroll
    for (int j = 0; j < 4; j++){
      run += d[j];
      const int q = base + run;
      kis[MMEM + t*4 + j] = q;
      ki[b*SS + MMEM + t*4 + j] = q;
      ki[b*SS + t*4 + j] = kis[t*4 + j];
    }
    __syncthreads();
    if (t < 64){
      const int qlo = kis[MMEM + t*16];
      const int qhi = kis[MMEM + t*16 + 15];
      int lo = 0, hi = SS;
      while (lo < hi){ int mid = (lo + hi) >> 1; if (kis[mid] < qlo) lo = mid + 1; else hi = mid; }
      const int s_lo = lo;
      lo = 0; hi = SS;
      const int tgt = qhi + 1;
      while (lo < hi){ int mid = (lo + hi) >> 1; if (kis[mid] < tgt) lo = mid + 1; else hi = mid; }
      int s_hi = lo;                              // exclusive
      const int cap = t*16 + 15 + MMEM + 1;       // causal cap
      if (s_hi > cap) s_hi = cap;
      ranges[(b << 6) + t] = make_int2(s_lo, s_hi);
    }
  }
}

// uk[b,n,s] = sum_h u[n,h]*k[b,s,n,h];  vr[n,j] = sum_h v[n,h]*r[j,n,h]
__global__ void bias_tables(const short* __restrict__ kbf, const short* __restrict__ rbf,
                            const float* __restrict__ u, const float* __restrict__ v,
                            float* __restrict__ uk, float* __restrict__ vr){
  int i = blockIdx.x * blockDim.x + threadIdx.x;
  const short* p; const float* w; float* outp;
  if (i < NB * NHD * SS){
    int s = i & 2047, n = (i >> 11) & 15, b = i >> 15;
    p = kbf + (size_t)(b * SS + s) * 1024 + n * 64;
    w = u + n * 64;
    outp = uk + (size_t)(b * NHD + n) * SS + s;
  } else {
    int j = i - NB * NHD * SS;
    if (j >= NHD * SS) return;
    int jj = j & 2047, n = j >> 11;
    p = rbf + (size_t)jj * 1024 + n * 64;
    w = v + n * 64;
    outp = vr + (size_t)n * SS + jj;
  }
  float acc = 0.f;
  #pragma unroll
  for (int c = 0; c < 8; c++){
    bf16x8 kv8 = *(const bf16x8*)(p + c * 8);
    float4 w0 = *(const float4*)(w + c * 8);
    float4 w1 = *(const float4*)(w + c * 8 + 4);
    acc += bf2f(kv8[0])*w0.x + bf2f(kv8[1])*w0.y + bf2f(kv8[2])*w0.z + bf2f(kv8[3])*w0.w
         + bf2f(kv8[4])*w1.x + bf2f(kv8[5])*w1.y + bf2f(kv8[6])*w1.z + bf2f(kv8[7])*w1.w;
  }
  *outp = acc;
}

// ------------- 64x64 GEMM core, BK=64, triple-buffer depth-2, ASM ds_read ---
// R14 core, unchanged (best measured: proj 51 us). R15 theory: the ~1 TB/s
// wall across R9/R11-R14 is Infinity-Cache bandwidth saturation from panel
// re-reads (~566 MB L2-miss traffic/dispatch = ~11 TB/s), not latency — so
// this round changes BLOCK->XCD placement (see proj_gemm), not the schedule.
__device__ __forceinline__ void gemm_core_64x64(const short* __restrict__ A,
                                                const short* __restrict__ BT,
                                                int row0, int col0,
                                                short* As, short* Bs,
                                                f32x4 (&acc)[2][2]){
  const int tid = threadIdx.x;
  const int lane = tid & 63, wv = tid >> 6;
  const int lcol = lane & 15, quad = lane >> 4;
  const int wr = (wv >> 1) * 32, wc = (wv & 1) * 32;
  const int sw = lcol & 7;
  const int ch0 = (quad ^ sw) * 8;
  const int ch1 = ((4 + quad) ^ sw) * 8;

  #pragma unroll
  for (int r = 0; r < 2; r++)
    #pragma unroll
    for (int c = 0; c < 2; c++) acc[r][c] = (f32x4){0.f, 0.f, 0.f, 0.f};

  // stage side: call j covers LDS slots j*256+tid -> row r = j*32 + (tid>>3),
  // phys chunk p = tid&7 must hold logical chunk p ^ (r&7)
  const int rs = tid >> 3, ps = tid & 7;
  const int ls = ps ^ (rs & 7);
  const short* gA = A  + (size_t)(row0 + rs) * 1024 + ls * 8;
  const short* gB = BT + (size_t)(col0 + rs) * 1024 + ls * 8;

  auto STAGE = [&](int k0, int bi){
    short* a = As + bi * 4096 + wv * 512;   // wave-uniform; HW adds lane*16B
    short* b = Bs + bi * 4096 + wv * 512;
    stage16(gA + k0,         a);
    stage16(gA + 32768 + k0, a + 2048);     // rows +32
    stage16(gB + k0,         b);
    stage16(gB + 32768 + k0, b + 2048);
  };

  const unsigned oa0 = lds_off(As) + (unsigned)(((wr + lcol) * 64 + ch0) * 2);
  const unsigned oa1 = lds_off(As) + (unsigned)(((wr + lcol) * 64 + ch1) * 2);
  const unsigned ob0 = lds_off(Bs) + (unsigned)(((wc + lcol) * 64 + ch0) * 2);
  const unsigned ob1 = lds_off(Bs) + (unsigned)(((wc + lcol) * 64 + ch1) * 2);

  // prologue: tiles 0,1 in flight (8 loads/thread outstanding)
  STAGE(0, 0);
  STAGE(64, 1);

  #pragma unroll 1
  for (int i = 0; i < 16; ++i){
    const int cur = i - (i / 3) * 3;        // i % 3
    if (i <= 13){
      const int nb = (i + 2) - ((i + 2) / 3) * 3;
      STAGE((i + 2) << 6, nb);
      asm volatile("s_waitcnt vmcnt(8)" ::: "memory");  // tile i landed; 8 in flight
    } else if (i == 14){
      asm volatile("s_waitcnt vmcnt(4)" ::: "memory");
    } else {
      asm volatile("s_waitcnt vmcnt(0)" ::: "memory");
    }
    __builtin_amdgcn_s_barrier();           // all waves' portions of tile i landed
    __builtin_amdgcn_sched_barrier(0);      // nothing crosses into the read region
    const unsigned bo = (unsigned)(cur * 8192);
    bf16x8 b00 = ds_read16<0>(ob0 + bo);
    bf16x8 b01 = ds_read16<0>(ob1 + bo);
    bf16x8 b10 = ds_read16<2048>(ob0 + bo);   // row +16
    bf16x8 b11 = ds_read16<2048>(ob1 + bo);
    bf16x8 a00 = ds_read16<0>(oa0 + bo);
    bf16x8 a01 = ds_read16<0>(oa1 + bo);
    bf16x8 a10 = ds_read16<2048>(oa0 + bo);   // row +16
    bf16x8 a11 = ds_read16<2048>(oa1 + bo);
    asm volatile("s_waitcnt lgkmcnt(0)" ::: "memory");  // ds_reads complete
    __builtin_amdgcn_sched_barrier(0);      // rule #18: pin MFMAs after the wait
    acc[0][0] = __builtin_amdgcn_mfma_f32_16x16x32_bf16(a00, b00, acc[0][0], 0, 0, 0);
    acc[0][0] = __builtin_amdgcn_mfma_f32_16x16x32_bf16(a01, b01, acc[0][0], 0, 0, 0);
    acc[0][1] = __builtin_amdgcn_mfma_f32_16x16x32_bf16(a00, b10, acc[0][1], 0, 0, 0);
    acc[0][1] = __builtin_amdgcn_mfma_f32_16x16x32_bf16(a01, b11, acc[0][1], 0, 0, 0);
    acc[1][0] = __builtin_amdgcn_mfma_f32_16x16x32_bf16(a10, b00, acc[1][0], 0, 0, 0);
    acc[1][0] = __builtin_amdgcn_mfma_f32_16x16x32_bf16(a11, b01, acc[1][0], 0, 0, 0);
    acc[1][1] = __builtin_amdgcn_mfma_f32_16x16x32_bf16(a10, b10, acc[1][1], 0, 0, 0);
    acc[1][1] = __builtin_amdgcn_mfma_f32_16x16x32_bf16(a11, b11, acc[1][1], 0, 0, 0);
    __builtin_amdgcn_sched_barrier(0);      // keep MFMAs inside this iteration
    __builtin_amdgcn_s_barrier();           // buf[cur] safe to overwrite
  }
}

// Fused projection GEMM (64x64 tiles): blockIdx.z selects job:
//   z=0: kbf = kv @ WkT                      (4096 rows, bx<64)
//   z=1: vT  = kv @ WvT, per-head transposed (4096 rows, bx<64)
//   z=2: qb  = x @ WqT   (x in-place from kv rows [M..S); bx<32)
//   z=3: rbf = rel @ WrT (2048 rows; bx<32) + row-band skip
// R15: XCD-locality swizzle. Dispatch round-robins blocks across the 8 XCDs
// (i -> XCD i%8). Map i = (chunk_hi, q, xcd) -> bx = chunk_hi*8+xcd, by = q,
// so ALL 16 column-blocks of a row-panel land on ONE XCD: the A-panel is
// fetched from L3 once and served 15x from that XCD's L2, and the 2 MB
// B-matrix stays L2-resident per z. Cuts ~566 MB/dispatch of L3 re-read
// traffic (the ~1 TB/s wall of R9-R14) to ~25 MB. Bijective: perf-only.
__global__ __launch_bounds__(256) void proj_gemm(
    const short* __restrict__ kv, const short* __restrict__ relb,
    const short* __restrict__ WkT, const short* __restrict__ WvT,
    const short* __restrict__ WqT, const short* __restrict__ WrT,
    short* __restrict__ kbf, short* __restrict__ vT,
    short* __restrict__ qb, short* __restrict__ rbf,
    const int2* __restrict__ ranges){
  const int z = blockIdx.z;
  const int iswz = blockIdx.x;               // [0,1024)
  const int xcd = iswz & 7, jj = iswz >> 3;
  const int bx = ((jj >> 4) << 3) | xcd;     // row tile [0,64)
  const int col0 = (jj & 15) * 64;           // col tile
  const int tid = threadIdx.x;
  const short* A; const short* BT;
  int row0 = bx * 64, qbb = 0;
  __shared__ int s_jm;
  if (z == 0 || z == 1){
    const int bb = row0 >> 11;         // batch
    const int srow = row0 & 2047;      // s-index of tile start
    if (srow + 64 <= ranges[bb << 6].x) return;   // dead K/V rows
    A = kv; BT = (z == 0) ? WkT : WvT;
  }
  else if (z == 2){
    if (bx >= 32) return;
    qbb = bx >> 4;                       // batch
    A = kv + (size_t)(qbb * SS + MMEM) * 1024;   // x rows live inside kv
    row0 = (bx & 15) * 64;
    BT = WqT;
  }
  else {
    if (bx >= 32) return;
    if (tid == 0) s_jm = 0x7fffffff;
    __syncthreads();
    if (tid < 128){
      int2 e = ranges[tid];
      int jr = (e.x & ~63) - ((tid & 63) << 4) + 1008;
      atomicMin(&s_jm, jr);
    }
    __syncthreads();
    if (row0 + 64 <= s_jm) return;
    A = relb; BT = WrT;
  }

  __shared__ __align__(16) short As[3 * 64 * 64];
  __shared__ __align__(16) short Bs[3 * 64 * 64];
  f32x4 acc[2][2];
  gemm_core_64x64(A, BT, row0, col0, As, Bs, acc);

  const int lane = threadIdx.x & 63, wv = threadIdx.x >> 6;
  const int lcol = lane & 15, quad = lane >> 4;
  const int wr = (wv >> 1) * 32, wc = (wv & 1) * 32;
  #pragma unroll
  for (int c = 0; c < 2; c++){
    const int cc = col0 + wc + c*16 + lcol;
    #pragma unroll
    for (int r = 0; r < 2; r++){
      #pragma unroll
      for (int ri = 0; ri < 4; ri++){
        const int rr = row0 + wr + r*16 + quad*4 + ri;
        float val = acc[r][c][ri];
        if (z == 0){
          kbf[(size_t)rr * 1024 + cc] = f2bf(val);
        } else if (z == 1){
          int b = rr >> 11, s = rr & 2047;
          vT[(size_t)(((b << 4) + (cc >> 6)) * 64 + (cc & 63)) * 2048 + s] = f2bf(val);
        } else if (z == 2){
          qb[((size_t)(qbb * TT) + rr) * 1024 + cc] = f2bf(val);
        } else {
          rbf[(size_t)rr * 1024 + cc] = f2bf(val);
        }
      }
    }
  }
}

// Output projection: out = attn @ WoT + b_out (f32 out, 2048 rows)
// Same XCD-locality swizzle: 512 blocks, 16 col-blocks per row-panel pinned
// to one XCD.
__global__ __launch_bounds__(256) void out_gemm(const short* __restrict__ A,
                                                const short* __restrict__ BT,
                                                const float* __restrict__ bias,
                                                float* __restrict__ C){
  const int iswz = blockIdx.x;               // [0,512)
  const int xcd = iswz & 7, jj = iswz >> 3;
  const int p = ((jj >> 4) << 3) | xcd;      // row tile [0,32)
  const int row0 = p * 64, col0 = (jj & 15) * 64;
  __shared__ __align__(16) short As[3 * 64 * 64];
  __shared__ __align__(16) short Bs[3 * 64 * 64];
  f32x4 acc[2][2];
  gemm_core_64x64(A, BT, row0, col0, As, Bs, acc);

  const int lane = threadIdx.x & 63, wv = threadIdx.x >> 6;
  const int lcol = lane & 15, quad = lane >> 4;
  const int wr = (wv >> 1) * 32, wc = (wv & 1) * 32;
  #pragma unroll
  for (int c = 0; c < 2; c++){
    const int cc = col0 + wc + c*16 + lcol;
    const float bb = bias[cc];
    #pragma unroll
    for (int r = 0; r < 2; r++)
      #pragma unroll
      for (int ri = 0; ri < 4; ri++){
        const int rr = row0 + wr + r*16 + quad*4 + ri;
        C[(size_t)rr * 1024 + cc] = acc[r][c][ri] + bb;
      }
  }
}

// ---------------- flash attention: one wave per 16-row q-group --------------
// grid 2048 x 64 threads. XCD swizzle (L2 working set per XCD ~3.6 MB).
// Each wave sweeps ONLY the valid k-tile interval from ranges[].
__global__ __launch_bounds__(64) void attn_kernel(const short* __restrict__ qb,
                            const short* __restrict__ rbf,
                            const short* __restrict__ kk, const short* __restrict__ vT,
                            const int* __restrict__ ki,
                            const float* __restrict__ uk, const float* __restrict__ vr,
                            const int2* __restrict__ ranges,
                            short* __restrict__ attn_out){
  const int blk = blockIdx.x;
  const int xcd = blk & 7;
  const int idx = blk >> 3;                 // [0,256)
  const int bn  = (xcd << 2) | (idx >> 6);  // 4 (b,n) groups per XCD
  const int t16 = (idx & 63) * 16;
  const int n = bn & 15;
  const int b = bn >> 4;
  const int lane = threadIdx.x & 63;
  const int quad = lane >> 4, lcol = lane & 15;

  __shared__ __align__(16) short pb[16 * 72];

  const short* qp = qb + (size_t)(b * TT + t16 + lcol) * 1024 + n * 64 + quad * 8;
  bf16x8 aq0 = *(const bf16x8*)(qp);
  bf16x8 aq1 = *(const bf16x8*)(qp + 32);

  int trow[4], qi_r[4], sl[4];
  bool hi[4];
  #pragma unroll
  for (int r = 0; r < 4; r++){
    trow[r] = t16 + quad * 4 + r;
    qi_r[r] = ki[b * SS + MMEM + trow[r]];
    const int rt = quad * 4 + r;
    const int off = lcol + 15 - rt;
    sl[r] = quad * 16 + (off & 15);
    hi[r] = off >= 16;
  }

  float m_run[4], l_run[4];
  f32x4 o[4];
  #pragma unroll
  for (int r = 0; r < 4; r++){ m_run[r] = -1e30f; l_run[r] = 0.f; }
  #pragma unroll
  for (int c = 0; c < 4; c++) o[c] = (f32x4){0.f, 0.f, 0.f, 0.f};

  const float scale = 0.125f;
  const size_t vt_base = (size_t)((b * NHD + n) * HD);
  const short* rb_head = rbf + n * 64;
  const float* uk_row = uk + (size_t)(b * NHD + n) * SS;
  const float* vr_row = vr + (size_t)n * SS;

  const int2 rg = ranges[(b << 6) + (t16 >> 4)];
  const int kt0 = rg.x >> 6, kt1 = (rg.y - 1) >> 6;

  for (int kt = kt0; kt <= kt1; kt++){
    const int s0 = kt * 64;
    // ---- S = Q . K^T  (+ uk column bias) ----
    f32x4 sacc[4];
    float ukc[4];
    #pragma unroll
    for (int c = 0; c < 4; c++){
      const short* kp = kk + (size_t)(b * SS + s0 + 16 * c + lcol) * 1024 + n * 64 + quad * 8;
      bf16x8 b0 = *(const bf16x8*)(kp);
      bf16x8 b1 = *(const bf16x8*)(kp + 32);
      f32x4 z = (f32x4){0.f, 0.f, 0.f, 0.f};
      z = __builtin_amdgcn_mfma_f32_16x16x32_bf16(aq0, b0, z, 0, 0, 0);
      z = __builtin_amdgcn_mfma_f32_16x16x32_bf16(aq1, b1, z, 0, 0, 0);
      sacc[c] = z;
      ukc[c] = uk_row[s0 + 16 * c + lcol];
    }
    int ki_c[4];
    #pragma unroll
    for (int c = 0; c < 4; c++) ki_c[c] = ki[b * SS + s0 + 16 * c + lcol];

    // ---- D = Q . R^T (+ vr column bias) over the 80-row window ----
    const int j0 = s0 - t16 + 1008;   // >= 0 always
    f32x4 Dw[5];
    #pragma unroll
    for (int c5 = 0; c5 < 5; c5++){
      int jr = j0 + 16 * c5 + lcol;
      jr = (jr > SS - 1) ? (SS - 1) : jr;   // clamped rows are causally masked
      const short* rp = rb_head + (size_t)jr * 1024 + quad * 8;
      bf16x8 r0 = *(const bf16x8*)(rp);
      bf16x8 r1 = *(const bf16x8*)(rp + 32);
      f32x4 z = (f32x4){0.f, 0.f, 0.f, 0.f};
      z = __builtin_amdgcn_mfma_f32_16x16x32_bf16(aq0, r0, z, 0, 0, 0);
      z = __builtin_amdgcn_mfma_f32_16x16x32_bf16(aq1, r1, z, 0, 0, 0);
      const float vrj = vr_row[jr];
      #pragma unroll
      for (int r = 0; r < 4; r++) z[r] += vrj;
      Dw[c5] = z;
    }

    // ---- bias shift (Toeplitz) + mask + logits ----
    float p[4][4];
    float rowmax[4];
    #pragma unroll
    for (int r = 0; r < 4; r++) rowmax[r] = -1e30f;
    #pragma unroll
    for (int c = 0; c < 4; c++){
      const int s = s0 + 16 * c + lcol;
      #pragma unroll
      for (int r = 0; r < 4; r++){
        const float v0 = __shfl(Dw[c][r], sl[r], 64);
        const float v1 = __shfl(Dw[c + 1][r], sl[r], 64);
        const float bd = hi[r] ? v1 : v0;
        float lg = (sacc[c][r] + ukc[c] + bd) * scale;
        const bool valid = (s <= trow[r] + MMEM) && (ki_c[c] == qi_r[r]);
        lg = valid ? lg : -1e30f;
        p[c][r] = lg;
        rowmax[r] = fmaxf(rowmax[r], lg);
      }
    }
    // ---- online softmax ----
    #pragma unroll
    for (int r = 0; r < 4; r++){
      float vmx = rowmax[r];
      #pragma unroll
      for (int off = 1; off < 16; off <<= 1) vmx = fmaxf(vmx, __shfl_xor(vmx, off, 64));
      float mnew = fmaxf(m_run[r], vmx);
      float alpha = __expf(m_run[r] - mnew);
      m_run[r] = mnew;
      l_run[r] *= alpha;
      #pragma unroll
      for (int c = 0; c < 4; c++) o[c][r] *= alpha;
    }
    float psum[4] = {0.f, 0.f, 0.f, 0.f};
    #pragma unroll
    for (int c = 0; c < 4; c++)
      #pragma unroll
      for (int r = 0; r < 4; r++){
        float pv = __expf(p[c][r] - m_run[r]);
        p[c][r] = pv;
        psum[r] += pv;
      }
    #pragma unroll
    for (int r = 0; r < 4; r++){
      float vs = psum[r];
      #pragma unroll
      for (int off = 1; off < 16; off <<= 1) vs += __shfl_xor(vs, off, 64);
      l_run[r] += vs;
    }
    // ---- P: C-layout -> A-layout via LDS (wave-synchronous) ----
    #pragma unroll
    for (int c = 0; c < 4; c++)
      #pragma unroll
      for (int r = 0; r < 4; r++)
        pb[(quad * 4 + r) * 72 + 16 * c + lcol] = f2bf(p[c][r]);
    bf16x8 pa0 = *(const bf16x8*)(&pb[lcol * 72 + quad * 8]);
    bf16x8 pa1 = *(const bf16x8*)(&pb[lcol * 72 + 32 + quad * 8]);
    // ---- O += P . V ----
    #pragma unroll
    for (int c = 0; c < 4; c++){
      const short* vtp = vT + (vt_base + c * 16 + lcol) * (size_t)SS + s0 + quad * 8;
      bf16x8 bv0 = *(const bf16x8*)(vtp);
      bf16x8 bv1 = *(const bf16x8*)(vtp + 32);
      o[c] = __builtin_amdgcn_mfma_f32_16x16x32_bf16(pa0, bv0, o[c], 0, 0, 0);
      o[c] = __builtin_amdgcn_mfma_f32_16x16x32_bf16(pa1, bv1, o[c], 0, 0, 0);
    }
  }

  // ---- epilogue: normalize, store bf16 attn [B*T, N*H] ----
  #pragma unroll
  for (int r = 0; r < 4; r++){
    const float inv = 1.f / l_run[r];
    const int t = trow[r];
    #pragma unroll
    for (int c = 0; c < 4; c++)
      attn_out[(size_t)(b * TT + t) * 1024 + n * 64 + c * 16 + lcol] = f2bf(o[c][r] * inv);
  }
}

// ---------------- launcher ----------------
extern "C" void kernel_launch(void* const* d_in, const int* in_sizes, int n_in,
                              void* d_out, int out_size, void* d_ws, size_t ws_size,
                              hipStream_t stream){
  const float* x      = (const float*)d_in[0];
  const float* rel    = (const float*)d_in[1];
  const float* memory = (const float*)d_in[2];
  const int*   episode_idx = (const int*)d_in[3];
  const int*   dones  = (const int*)d_in[4];
  const float* Wq  = (const float*)d_in[5];
  const float* Wk  = (const float*)d_in[6];
  const float* Wv  = (const float*)d_in[7];
  const float* Wr  = (const float*)d_in[8];
  const float* u   = (const float*)d_in[9];
  const float* v   = (const float*)d_in[10];
  const float* Wout  = (const float*)d_in[11];
  const float* b_out = (const float*)d_in[12];
  float* out = (float*)d_out;

  char* ws = (char*)d_ws;
  size_t off = 0;
  auto alloc = [&](size_t bytes) -> char* {
    char* p = ws + off;
    off += (bytes + 255) & ~(size_t)255;
    return p;
  };
  short* kv_bf  = (short*)alloc((size_t)NB * SS * FF * 2);
  short* rel_bf = (short*)alloc((size_t)SS * FF * 2);
  short* WqT    = (short*)alloc((size_t)FF * 1024 * 2);
  short* WkT    = (short*)alloc((size_t)FF * 1024 * 2);
  short* WvT    = (short*)alloc((size_t)FF * 1024 * 2);
  short* WrT    = (short*)alloc((size_t)FF * 1024 * 2);
  short* WoT    = (short*)alloc((size_t)FF * 1024 * 2);
  short* qbuf   = (short*)alloc((size_t)NB * TT * 1024 * 2);
  short* kbf    = (short*)alloc((size_t)NB * SS * 1024 * 2);
  short* vTb    = (short*)alloc((size_t)NB * SS * 1024 * 2);
  short* rbf    = (short*)alloc((size_t)SS * 1024 * 2);
  int*   ki     = (int*)  alloc((size_t)NB * SS * 4);
  int2*  ranges = (int2*) alloc((size_t)NB * 64 * 8);
  float* ukT    = (float*)alloc((size_t)NB * NHD * SS * 4);
  float* vrT    = (float*)alloc((size_t)NHD * SS * 4);
  short* attn   = (short*)alloc((size_t)NB * TT * 1024 * 2);
  (void)ws_size; (void)in_sizes; (void)n_in; (void)out_size;

  // merged prep: pack + 5x transpose-cast + scan (one launch, R15)
  prep_kernel<<<NKVB + NTRB + NB, 256, 0, stream>>>(
      memory, x, rel, episode_idx, dones,
      Wq, Wk, Wv, Wr, Wout,
      kv_bf, rel_bf, WqT, WkT, WvT, WrT, WoT, ki, ranges);

  // fused projections, 64x64 tiles, R14 core + XCD-locality swizzle (R15)
  proj_gemm<<<dim3(1024, 1, 4), 256, 0, stream>>>(kv_bf, rel_bf,
                                                  WkT, WvT, WqT, WrT,
                                                  kbf, vTb, qbuf, rbf, ranges);

  // u·k / v·r column-bias tables
  bias_tables<<<(NB*NHD*SS + NHD*SS + 255)/256, 256, 0, stream>>>(kbf, rbf, u, v, ukT, vrT);

  // attention: one wave per 16-row q-group, valid-interval sweep only
  attn_kernel<<<2048, 64, 0, stream>>>(qbuf, rbf, kbf, vTb, ki, ukT, vrT, ranges, attn);

  // output projection (XCD-locality swizzle)
  out_gemm<<<512, 256, 0, stream>>>(attn, WoT, b_out, out);
}

// Round 6
// 191.017 us; speedup vs baseline: 1.2671x; 1.0585x over previous
//
#include <hip/hip_runtime.h>
#include <cstdint>
#include <cstddef>

// Problem constants
#define NB 2
#define TT 1024
#define MMEM 1024
#define SS 2048   // M + T
#define FF 1024
#define NHD 16    // heads
#define HD 64    // head dim

typedef __attribute__((ext_vector_type(8))) short bf16x8;
typedef __attribute__((ext_vector_type(4))) float f32x4;

__device__ __forceinline__ float bf2f(short s){
  unsigned u = ((unsigned)(unsigned short)s) << 16;
  float f; __builtin_memcpy(&f, &u, 4); return f;
}
__device__ __forceinline__ short f2bf(float f){
  unsigned u; __builtin_memcpy(&u, &f, 4);
  u += 0x7fffu + ((u >> 16) & 1u);   // RNE
  return (short)(u >> 16);
}

// async global->LDS, 16 B per lane; LDS dest must be WAVE-UNIFORM base,
// HW scatters lane i to base + i*16 (m104).
typedef const __attribute__((address_space(1))) void gv_t;
typedef __attribute__((address_space(3))) void lv_t;
__device__ __forceinline__ void stage16(const void* g, void* l){
  __builtin_amdgcn_global_load_lds((gv_t*)g, (lv_t*)l, 16, 0, 0);
}

// LDS byte offset of a generic pointer into __shared__ (HK lds_byte pattern).
typedef __attribute__((address_space(3))) const short ls3_t;
__device__ __forceinline__ unsigned lds_off(const short* p){
  return (unsigned)(size_t)(ls3_t*)p;
}

// inline-asm ds_read_b128. No "memory" clobber — the compiler must NOT see an
// LDS-read dependency on the outstanding global_load_lds queue, or it inserts
// its own s_waitcnt vmcnt(0) (the R11-R13 silent drain). Ordering is manual:
// counted vmcnt + s_barrier + sched_barrier(0), lgkmcnt(0)+sched_barrier(0)
// before the consuming MFMAs (rule #18).
template<int OFF>
__device__ __forceinline__ bf16x8 ds_read16(unsigned a){
  bf16x8 d;
  if constexpr (OFF == 0)
    asm volatile("ds_read_b128 %0, %1" : "=v"(d) : "v"(a));
  else
    asm volatile("ds_read_b128 %0, %1 offset:2048" : "=v"(d) : "v"(a));
  return d;
}

// ---------------- merged prep kernel ----------------
// build_inputs + transpose_cast5 + scan fused into ONE launch (R15).
#define NKVB 6144
#define NTRB 5120

__global__ __launch_bounds__(256) void prep_kernel(
    const float* __restrict__ mem, const float* __restrict__ x,
    const float* __restrict__ rel,
    const int* __restrict__ episode_idx, const int* __restrict__ dones,
    const float* __restrict__ w0, const float* __restrict__ w1,
    const float* __restrict__ w2, const float* __restrict__ w3,
    const float* __restrict__ w4,
    short* __restrict__ kv, short* __restrict__ relo,
    short* __restrict__ o0, short* __restrict__ o1,
    short* __restrict__ o2, short* __restrict__ o3, short* __restrict__ o4,
    int* __restrict__ ki, int2* __restrict__ ranges){
  const int blk = blockIdx.x;
  const int tid = threadIdx.x;

  if (blk < NKVB){
    // ---- pack: kv_bf = bf16(concat(memory, x)); rel_bf = bf16(rel) ----
    int i = blk * 256 + tid;  // float4 index
    const int nkv = NB * SS * FF / 4;
    const float* src; short* dst;
    if (i < nkv){
      int idx = i * 4;
      int row = idx >> 10, col = idx & 1023;
      int b = row >> 11, s = row & 2047;
      src = (s < MMEM) ? (mem + ((size_t)b*MMEM + s)*FF + col)
                       : (x   + ((size_t)b*TT + (s - MMEM))*FF + col);
      dst = kv + (size_t)i * 4;
    } else {
      int j = i - nkv;
      src = rel + (size_t)j * 4;
      dst = relo + (size_t)j * 4;
    }
    float4 v = *(const float4*)src;
    short4 o; o.x = f2bf(v.x); o.y = f2bf(v.y); o.z = f2bf(v.z); o.w = f2bf(v.w);
    *(short4*)dst = o;
    return;
  }

  if (blk < NKVB + NTRB){
    // ---- transpose-cast: out_z[c][r] = bf16(in_z[r][c]), 1024x1024 ----
    const int j = blk - NKVB;
    const int z5 = j >> 10;
    const int rem = j & 1023;
    const int by5 = rem >> 5, bx5 = rem & 31;
    const float* in; short* out;
    switch (z5){
      case 0: in = w0; out = o0; break;
      case 1: in = w1; out = o1; break;
      case 2: in = w2; out = o2; break;
      case 3: in = w3; out = o3; break;
      default: in = w4; out = o4; break;
    }
    __shared__ float tile[32][33];
    const int bx = bx5 * 32, by = by5 * 32;
    const int tx = tid & 31, ty = tid >> 5;
    for (int jj = ty; jj < 32; jj += 8)
      tile[jj][tx] = in[(size_t)(by + jj)*1024 + bx + tx];
    __syncthreads();
    for (int jj = ty; jj < 32; jj += 8)
      out[(size_t)(bx + jj)*1024 + by + tx] = f2bf(tile[tx][jj]);
    return;
  }

  // ---- scan (256 threads): ki + per-16-row-group valid-key ranges ----
  {
    const int b = blk - (NKVB + NTRB);
    __shared__ int kis[SS];
    __shared__ int wsum[4];
    const int t = tid;
    const int lane = t & 63, wv = t >> 6;
    #pragma unroll
    for (int j = 0; j < 4; j++) kis[t*4 + j] = episode_idx[b*MMEM + t*4 + j];
    int d[4]; int s = 0;
    #pragma unroll
    for (int j = 0; j < 4; j++){ d[j] = dones[b*TT + t*4 + j]; s += d[j]; }
    int v = s;
    #pragma unroll
    for (int off = 1; off < 64; off <<= 1){
      int tmp = __shfl_up(v, off, 64);
      if (lane >= off) v += tmp;
    }
    if (lane == 63) wsum[wv] = v;
    __syncthreads();                      // kis[0:1024] + wsum visible
    int add = 0;
    for (int w = 0; w < wv; w++) add += wsum[w];
    const int base = kis[MMEM - 1];
    int run = add + v - s;                // exclusive prefix before this thread
    #pragma unroll
    for (int j = 0; j < 4; j++){
      run += d[j];
      const int q = base + run;
      kis[MMEM + t*4 + j] = q;
      ki[b*SS + MMEM + t*4 + j] = q;
      ki[b*SS + t*4 + j] = kis[t*4 + j];
    }
    __syncthreads();
    if (t < 64){
      const int qlo = kis[MMEM + t*16];
      const int qhi = kis[MMEM + t*16 + 15];
      int lo = 0, hi = SS;
      while (lo < hi){ int mid = (lo + hi) >> 1; if (kis[mid] < qlo) lo = mid + 1; else hi = mid; }
      const int s_lo = lo;
      lo = 0; hi = SS;
      const int tgt = qhi + 1;
      while (lo < hi){ int mid = (lo + hi) >> 1; if (kis[mid] < tgt) lo = mid + 1; else hi = mid; }
      int s_hi = lo;                              // exclusive
      const int cap = t*16 + 15 + MMEM + 1;       // causal cap
      if (s_hi > cap) s_hi = cap;
      ranges[(b << 6) + t] = make_int2(s_lo, s_hi);
    }
  }
}

// uk[b,n,s] = sum_h u[n,h]*k[b,s,n,h];  vr[n,j] = sum_h v[n,h]*r[j,n,h]
__global__ void bias_tables(const short* __restrict__ kbf, const short* __restrict__ rbf,
                            const float* __restrict__ u, const float* __restrict__ v,
                            float* __restrict__ uk, float* __restrict__ vr){
  int i = blockIdx.x * blockDim.x + threadIdx.x;
  const short* p; const float* w; float* outp;
  if (i < NB * NHD * SS){
    int s = i & 2047, n = (i >> 11) & 15, b = i >> 15;
    p = kbf + (size_t)(b * SS + s) * 1024 + n * 64;
    w = u + n * 64;
    outp = uk + (size_t)(b * NHD + n) * SS + s;
  } else {
    int j = i - NB * NHD * SS;
    if (j >= NHD * SS) return;
    int jj = j & 2047, n = j >> 11;
    p = rbf + (size_t)jj * 1024 + n * 64;
    w = v + n * 64;
    outp = vr + (size_t)n * SS + jj;
  }
  float acc = 0.f;
  #pragma unroll
  for (int c = 0; c < 8; c++){
    bf16x8 kv8 = *(const bf16x8*)(p + c * 8);
    float4 w0 = *(const float4*)(w + c * 8);
    float4 w1 = *(const float4*)(w + c * 8 + 4);
    acc += bf2f(kv8[0])*w0.x + bf2f(kv8[1])*w0.y + bf2f(kv8[2])*w0.z + bf2f(kv8[3])*w0.w
         + bf2f(kv8[4])*w1.x + bf2f(kv8[5])*w1.y + bf2f(kv8[6])*w1.z + bf2f(kv8[7])*w1.w;
  }
  *outp = acc;
}

// ------------- 64x64 GEMM core, BK=64, triple-buffer depth-2, ASM ds_read ---
// R14 core + R15 XCD-locality placement. Unchanged this round.
__device__ __forceinline__ void gemm_core_64x64(const short* __restrict__ A,
                                                const short* __restrict__ BT,
                                                int row0, int col0,
                                                short* As, short* Bs,
                                                f32x4 (&acc)[2][2]){
  const int tid = threadIdx.x;
  const int lane = tid & 63, wv = tid >> 6;
  const int lcol = lane & 15, quad = lane >> 4;
  const int wr = (wv >> 1) * 32, wc = (wv & 1) * 32;
  const int sw = lcol & 7;
  const int ch0 = (quad ^ sw) * 8;
  const int ch1 = ((4 + quad) ^ sw) * 8;

  #pragma unroll
  for (int r = 0; r < 2; r++)
    #pragma unroll
    for (int c = 0; c < 2; c++) acc[r][c] = (f32x4){0.f, 0.f, 0.f, 0.f};

  // stage side: call j covers LDS slots j*256+tid -> row r = j*32 + (tid>>3),
  // phys chunk p = tid&7 must hold logical chunk p ^ (r&7)
  const int rs = tid >> 3, ps = tid & 7;
  const int ls = ps ^ (rs & 7);
  const short* gA = A  + (size_t)(row0 + rs) * 1024 + ls * 8;
  const short* gB = BT + (size_t)(col0 + rs) * 1024 + ls * 8;

  auto STAGE = [&](int k0, int bi){
    short* a = As + bi * 4096 + wv * 512;   // wave-uniform; HW adds lane*16B
    short* b = Bs + bi * 4096 + wv * 512;
    stage16(gA + k0,         a);
    stage16(gA + 32768 + k0, a + 2048);     // rows +32
    stage16(gB + k0,         b);
    stage16(gB + 32768 + k0, b + 2048);
  };

  const unsigned oa0 = lds_off(As) + (unsigned)(((wr + lcol) * 64 + ch0) * 2);
  const unsigned oa1 = lds_off(As) + (unsigned)(((wr + lcol) * 64 + ch1) * 2);
  const unsigned ob0 = lds_off(Bs) + (unsigned)(((wc + lcol) * 64 + ch0) * 2);
  const unsigned ob1 = lds_off(Bs) + (unsigned)(((wc + lcol) * 64 + ch1) * 2);

  // prologue: tiles 0,1 in flight (8 loads/thread outstanding)
  STAGE(0, 0);
  STAGE(64, 1);

  #pragma unroll 1
  for (int i = 0; i < 16; ++i){
    const int cur = i - (i / 3) * 3;        // i % 3
    if (i <= 13){
      const int nb = (i + 2) - ((i + 2) / 3) * 3;
      STAGE((i + 2) << 6, nb);
      asm volatile("s_waitcnt vmcnt(8)" ::: "memory");  // tile i landed; 8 in flight
    } else if (i == 14){
      asm volatile("s_waitcnt vmcnt(4)" ::: "memory");
    } else {
      asm volatile("s_waitcnt vmcnt(0)" ::: "memory");
    }
    __builtin_amdgcn_s_barrier();           // all waves' portions of tile i landed
    __builtin_amdgcn_sched_barrier(0);      // nothing crosses into the read region
    const unsigned bo = (unsigned)(cur * 8192);
    bf16x8 b00 = ds_read16<0>(ob0 + bo);
    bf16x8 b01 = ds_read16<0>(ob1 + bo);
    bf16x8 b10 = ds_read16<2048>(ob0 + bo);   // row +16
    bf16x8 b11 = ds_read16<2048>(ob1 + bo);
    bf16x8 a00 = ds_read16<0>(oa0 + bo);
    bf16x8 a01 = ds_read16<0>(oa1 + bo);
    bf16x8 a10 = ds_read16<2048>(oa0 + bo);   // row +16
    bf16x8 a11 = ds_read16<2048>(oa1 + bo);
    asm volatile("s_waitcnt lgkmcnt(0)" ::: "memory");  // ds_reads complete
    __builtin_amdgcn_sched_barrier(0);      // rule #18: pin MFMAs after the wait
    acc[0][0] = __builtin_amdgcn_mfma_f32_16x16x32_bf16(a00, b00, acc[0][0], 0, 0, 0);
    acc[0][0] = __builtin_amdgcn_mfma_f32_16x16x32_bf16(a01, b01, acc[0][0], 0, 0, 0);
    acc[0][1] = __builtin_amdgcn_mfma_f32_16x16x32_bf16(a00, b10, acc[0][1], 0, 0, 0);
    acc[0][1] = __builtin_amdgcn_mfma_f32_16x16x32_bf16(a01, b11, acc[0][1], 0, 0, 0);
    acc[1][0] = __builtin_amdgcn_mfma_f32_16x16x32_bf16(a10, b00, acc[1][0], 0, 0, 0);
    acc[1][0] = __builtin_amdgcn_mfma_f32_16x16x32_bf16(a11, b01, acc[1][0], 0, 0, 0);
    acc[1][1] = __builtin_amdgcn_mfma_f32_16x16x32_bf16(a10, b10, acc[1][1], 0, 0, 0);
    acc[1][1] = __builtin_amdgcn_mfma_f32_16x16x32_bf16(a11, b11, acc[1][1], 0, 0, 0);
    __builtin_amdgcn_sched_barrier(0);      // keep MFMAs inside this iteration
    __builtin_amdgcn_s_barrier();           // buf[cur] safe to overwrite
  }
}

// Fused projection GEMM (64x64 tiles) + XCD-locality swizzle (R15).
__global__ __launch_bounds__(256) void proj_gemm(
    const short* __restrict__ kv, const short* __restrict__ relb,
    const short* __restrict__ WkT, const short* __restrict__ WvT,
    const short* __restrict__ WqT, const short* __restrict__ WrT,
    short* __restrict__ kbf, short* __restrict__ vT,
    short* __restrict__ qb, short* __restrict__ rbf,
    const int2* __restrict__ ranges){
  const int z = blockIdx.z;
  const int iswz = blockIdx.x;               // [0,1024)
  const int xcd = iswz & 7, jj = iswz >> 3;
  const int bx = ((jj >> 4) << 3) | xcd;     // row tile [0,64)
  const int col0 = (jj & 15) * 64;           // col tile
  const int tid = threadIdx.x;
  const short* A; const short* BT;
  int row0 = bx * 64, qbb = 0;
  __shared__ int s_jm;
  if (z == 0 || z == 1){
    const int bb = row0 >> 11;         // batch
    const int srow = row0 & 2047;      // s-index of tile start
    if (srow + 64 <= ranges[bb << 6].x) return;   // dead K/V rows
    A = kv; BT = (z == 0) ? WkT : WvT;
  }
  else if (z == 2){
    if (bx >= 32) return;
    qbb = bx >> 4;                       // batch
    A = kv + (size_t)(qbb * SS + MMEM) * 1024;   // x rows live inside kv
    row0 = (bx & 15) * 64;
    BT = WqT;
  }
  else {
    if (bx >= 32) return;
    if (tid == 0) s_jm = 0x7fffffff;
    __syncthreads();
    if (tid < 128){
      int2 e = ranges[tid];
      int jr = (e.x & ~63) - ((tid & 63) << 4) + 1008;
      atomicMin(&s_jm, jr);
    }
    __syncthreads();
    if (row0 + 64 <= s_jm) return;
    A = relb; BT = WrT;
  }

  __shared__ __align__(16) short As[3 * 64 * 64];
  __shared__ __align__(16) short Bs[3 * 64 * 64];
  f32x4 acc[2][2];
  gemm_core_64x64(A, BT, row0, col0, As, Bs, acc);

  const int lane = threadIdx.x & 63, wv = threadIdx.x >> 6;
  const int lcol = lane & 15, quad = lane >> 4;
  const int wr = (wv >> 1) * 32, wc = (wv & 1) * 32;
  #pragma unroll
  for (int c = 0; c < 2; c++){
    const int cc = col0 + wc + c*16 + lcol;
    #pragma unroll
    for (int r = 0; r < 2; r++){
      #pragma unroll
      for (int ri = 0; ri < 4; ri++){
        const int rr = row0 + wr + r*16 + quad*4 + ri;
        float val = acc[r][c][ri];
        if (z == 0){
          kbf[(size_t)rr * 1024 + cc] = f2bf(val);
        } else if (z == 1){
          int b = rr >> 11, s = rr & 2047;
          vT[(size_t)(((b << 4) + (cc >> 6)) * 64 + (cc & 63)) * 2048 + s] = f2bf(val);
        } else if (z == 2){
          qb[((size_t)(qbb * TT) + rr) * 1024 + cc] = f2bf(val);
        } else {
          rbf[(size_t)rr * 1024 + cc] = f2bf(val);
        }
      }
    }
  }
}

// Output projection: out = attn @ WoT + b_out (f32 out, 2048 rows)
__global__ __launch_bounds__(256) void out_gemm(const short* __restrict__ A,
                                                const short* __restrict__ BT,
                                                const float* __restrict__ bias,
                                                float* __restrict__ C){
  const int iswz = blockIdx.x;               // [0,512)
  const int xcd = iswz & 7, jj = iswz >> 3;
  const int p = ((jj >> 4) << 3) | xcd;      // row tile [0,32)
  const int row0 = p * 64, col0 = (jj & 15) * 64;
  __shared__ __align__(16) short As[3 * 64 * 64];
  __shared__ __align__(16) short Bs[3 * 64 * 64];
  f32x4 acc[2][2];
  gemm_core_64x64(A, BT, row0, col0, As, Bs, acc);

  const int lane = threadIdx.x & 63, wv = threadIdx.x >> 6;
  const int lcol = lane & 15, quad = lane >> 4;
  const int wr = (wv >> 1) * 32, wc = (wv & 1) * 32;
  #pragma unroll
  for (int c = 0; c < 2; c++){
    const int cc = col0 + wc + c*16 + lcol;
    const float bb = bias[cc];
    #pragma unroll
    for (int r = 0; r < 2; r++)
      #pragma unroll
      for (int ri = 0; ri < 4; ri++){
        const int rr = row0 + wr + r*16 + quad*4 + ri;
        C[(size_t)rr * 1024 + cc] = acc[r][c][ri] + bb;
      }
  }
}

// ---------------- flash attention: one wave per 16-row q-group --------------
// R16: load-batched iteration + VGPR uncap. R15's attn showed 42.6 us with
// VGPR_Count=64: the __launch_bounds__(64) cap forced the compiler to
// serialize the ~26 independent K/R/V loads per k-tile into load->wait->use
// chains (one tile's data alone needs ~104 VGPRs). __launch_bounds__(64,2)
// grants 256 VGPR at our actual occupancy (8 one-wave blocks/CU = 2/SIMD),
// and the body batch-issues K+R first (one latency for QK^T+D), then issues
// V loads BEFORE the shuffle/softmax phase so their latency hides under it.
// Pure load reordering — FP op order unchanged -> bit-identical output.
__global__ __launch_bounds__(64, 2) void attn_kernel(const short* __restrict__ qb,
                            const short* __restrict__ rbf,
                            const short* __restrict__ kk, const short* __restrict__ vT,
                            const int* __restrict__ ki,
                            const float* __restrict__ uk, const float* __restrict__ vr,
                            const int2* __restrict__ ranges,
                            short* __restrict__ attn_out){
  const int blk = blockIdx.x;
  const int xcd = blk & 7;
  const int idx = blk >> 3;                 // [0,256)
  const int bn  = (xcd << 2) | (idx >> 6);  // 4 (b,n) groups per XCD
  const int t16 = (idx & 63) * 16;
  const int n = bn & 15;
  const int b = bn >> 4;
  const int lane = threadIdx.x & 63;
  const int quad = lane >> 4, lcol = lane & 15;

  __shared__ __align__(16) short pb[16 * 72];

  const short* qp = qb + (size_t)(b * TT + t16 + lcol) * 1024 + n * 64 + quad * 8;
  bf16x8 aq0 = *(const bf16x8*)(qp);
  bf16x8 aq1 = *(const bf16x8*)(qp + 32);

  int trow[4], qi_r[4], sl[4];
  bool hi[4];
  #pragma unroll
  for (int r = 0; r < 4; r++){
    trow[r] = t16 + quad * 4 + r;
    qi_r[r] = ki[b * SS + MMEM + trow[r]];
    const int rt = quad * 4 + r;
    const int off = lcol + 15 - rt;
    sl[r] = quad * 16 + (off & 15);
    hi[r] = off >= 16;
  }

  float m_run[4], l_run[4];
  f32x4 o[4];
  #pragma unroll
  for (int r = 0; r < 4; r++){ m_run[r] = -1e30f; l_run[r] = 0.f; }
  #pragma unroll
  for (int c = 0; c < 4; c++) o[c] = (f32x4){0.f, 0.f, 0.f, 0.f};

  const float scale = 0.125f;
  const size_t vt_base = (size_t)((b * NHD + n) * HD);
  const short* rb_head = rbf + n * 64;
  const float* uk_row = uk + (size_t)(b * NHD + n) * SS;
  const float* vr_row = vr + (size_t)n * SS;

  const int2 rg = ranges[(b << 6) + (t16 >> 4)];
  const int kt0 = rg.x >> 6, kt1 = (rg.y - 1) >> 6;

  for (int kt = kt0; kt <= kt1; kt++){
    const int s0 = kt * 64;

    // ---- batched load phase 1: all K (8x bf16x8), all R (10x), scalars ----
    bf16x8 kb[4][2], rbr[5][2];
    float ukc[4], vrj[5];
    int ki_c[4], jrr[5];
    #pragma unroll
    for (int c = 0; c < 4; c++){
      const short* kp = kk + (size_t)(b * SS + s0 + 16 * c + lcol) * 1024 + n * 64 + quad * 8;
      kb[c][0] = *(const bf16x8*)(kp);
      kb[c][1] = *(const bf16x8*)(kp + 32);
      ukc[c] = uk_row[s0 + 16 * c + lcol];
      ki_c[c] = ki[b * SS + s0 + 16 * c + lcol];
    }
    const int j0 = s0 - t16 + 1008;   // >= 0 always
    #pragma unroll
    for (int c5 = 0; c5 < 5; c5++){
      int jr = j0 + 16 * c5 + lcol;
      jr = (jr > SS - 1) ? (SS - 1) : jr;   // clamped rows are causally masked
      jrr[c5] = jr;
      const short* rp = rb_head + (size_t)jr * 1024 + quad * 8;
      rbr[c5][0] = *(const bf16x8*)(rp);
      rbr[c5][1] = *(const bf16x8*)(rp + 32);
      vrj[c5] = vr_row[jr];
    }

    // ---- S = Q . K^T ----
    f32x4 sacc[4];
    #pragma unroll
    for (int c = 0; c < 4; c++){
      f32x4 z = (f32x4){0.f, 0.f, 0.f, 0.f};
      z = __builtin_amdgcn_mfma_f32_16x16x32_bf16(aq0, kb[c][0], z, 0, 0, 0);
      z = __builtin_amdgcn_mfma_f32_16x16x32_bf16(aq1, kb[c][1], z, 0, 0, 0);
      sacc[c] = z;
    }
    // ---- D = Q . R^T (+ vr column bias) over the 80-row window ----
    f32x4 Dw[5];
    #pragma unroll
    for (int c5 = 0; c5 < 5; c5++){
      f32x4 z = (f32x4){0.f, 0.f, 0.f, 0.f};
      z = __builtin_amdgcn_mfma_f32_16x16x32_bf16(aq0, rbr[c5][0], z, 0, 0, 0);
      z = __builtin_amdgcn_mfma_f32_16x16x32_bf16(aq1, rbr[c5][1], z, 0, 0, 0);
      const float vv = vrj[c5];
      #pragma unroll
      for (int r = 0; r < 4; r++) z[r] += vv;
      Dw[c5] = z;
    }

    // ---- batched load phase 2: V (latency hides under shuffles/softmax) ----
    bf16x8 vb[4][2];
    #pragma unroll
    for (int c = 0; c < 4; c++){
      const short* vtp = vT + (vt_base + c * 16 + lcol) * (size_t)SS + s0 + quad * 8;
      vb[c][0] = *(const bf16x8*)(vtp);
      vb[c][1] = *(const bf16x8*)(vtp + 32);
    }

    // ---- bias shift (Toeplitz) + mask + logits ----
    float p[4][4];
    float rowmax[4];
    #pragma unroll
    for (int r = 0; r < 4; r++) rowmax[r] = -1e30f;
    #pragma unroll
    for (int c = 0; c < 4; c++){
      const int s = s0 + 16 * c + lcol;
      #pragma unroll
      for (int r = 0; r < 4; r++){
        const float v0 = __shfl(Dw[c][r], sl[r], 64);
        const float v1 = __shfl(Dw[c + 1][r], sl[r], 64);
        const float bd = hi[r] ? v1 : v0;
        float lg = (sacc[c][r] + ukc[c] + bd) * scale;
        const bool valid = (s <= trow[r] + MMEM) && (ki_c[c] == qi_r[r]);
        lg = valid ? lg : -1e30f;
        p[c][r] = lg;
        rowmax[r] = fmaxf(rowmax[r], lg);
      }
    }
    // ---- online softmax ----
    #pragma unroll
    for (int r = 0; r < 4; r++){
      float vmx = rowmax[r];
      #pragma unroll
      for (int off = 1; off < 16; off <<= 1) vmx = fmaxf(vmx, __shfl_xor(vmx, off, 64));
      float mnew = fmaxf(m_run[r], vmx);
      float alpha = __expf(m_run[r] - mnew);
      m_run[r] = mnew;
      l_run[r] *= alpha;
      #pragma unroll
      for (int c = 0; c < 4; c++) o[c][r] *= alpha;
    }
    float psum[4] = {0.f, 0.f, 0.f, 0.f};
    #pragma unroll
    for (int c = 0; c < 4; c++)
      #pragma unroll
      for (int r = 0; r < 4; r++){
        float pv = __expf(p[c][r] - m_run[r]);
        p[c][r] = pv;
        psum[r] += pv;
      }
    #pragma unroll
    for (int r = 0; r < 4; r++){
      float vs = psum[r];
      #pragma unroll
      for (int off = 1; off < 16; off <<= 1) vs += __shfl_xor(vs, off, 64);
      l_run[r] += vs;
    }
    // ---- P: C-layout -> A-layout via LDS (wave-synchronous) ----
    #pragma unroll
    for (int c = 0; c < 4; c++)
      #pragma unroll
      for (int r = 0; r < 4; r++)
        pb[(quad * 4 + r) * 72 + 16 * c + lcol] = f2bf(p[c][r]);
    bf16x8 pa0 = *(const bf16x8*)(&pb[lcol * 72 + quad * 8]);
    bf16x8 pa1 = *(const bf16x8*)(&pb[lcol * 72 + 32 + quad * 8]);
    // ---- O += P . V ----
    #pragma unroll
    for (int c = 0; c < 4; c++){
      o[c] = __builtin_amdgcn_mfma_f32_16x16x32_bf16(pa0, vb[c][0], o[c], 0, 0, 0);
      o[c] = __builtin_amdgcn_mfma_f32_16x16x32_bf16(pa1, vb[c][1], o[c], 0, 0, 0);
    }
  }

  // ---- epilogue: normalize, store bf16 attn [B*T, N*H] ----
  #pragma unroll
  for (int r = 0; r < 4; r++){
    const float inv = 1.f / l_run[r];
    const int t = trow[r];
    #pragma unroll
    for (int c = 0; c < 4; c++)
      attn_out[(size_t)(b * TT + t) * 1024 + n * 64 + c * 16 + lcol] = f2bf(o[c][r] * inv);
  }
}

// ---------------- launcher ----------------
extern "C" void kernel_launch(void* const* d_in, const int* in_sizes, int n_in,
                              void* d_out, int out_size, void* d_ws, size_t ws_size,
                              hipStream_t stream){
  const float* x      = (const float*)d_in[0];
  const float* rel    = (const float*)d_in[1];
  const float* memory = (const float*)d_in[2];
  const int*   episode_idx = (const int*)d_in[3];
  const int*   dones  = (const int*)d_in[4];
  const float* Wq  = (const float*)d_in[5];
  const float* Wk  = (const float*)d_in[6];
  const float* Wv  = (const float*)d_in[7];
  const float* Wr  = (const float*)d_in[8];
  const float* u   = (const float*)d_in[9];
  const float* v   = (const float*)d_in[10];
  const float* Wout  = (const float*)d_in[11];
  const float* b_out = (const float*)d_in[12];
  float* out = (float*)d_out;

  char* ws = (char*)d_ws;
  size_t off = 0;
  auto alloc = [&](size_t bytes) -> char* {
    char* p = ws + off;
    off += (bytes + 255) & ~(size_t)255;
    return p;
  };
  short* kv_bf  = (short*)alloc((size_t)NB * SS * FF * 2);
  short* rel_bf = (short*)alloc((size_t)SS * FF * 2);
  short* WqT    = (short*)alloc((size_t)FF * 1024 * 2);
  short* WkT    = (short*)alloc((size_t)FF * 1024 * 2);
  short* WvT    = (short*)alloc((size_t)FF * 1024 * 2);
  short* WrT    = (short*)alloc((size_t)FF * 1024 * 2);
  short* WoT    = (short*)alloc((size_t)FF * 1024 * 2);
  short* qbuf   = (short*)alloc((size_t)NB * TT * 1024 * 2);
  short* kbf    = (short*)alloc((size_t)NB * SS * 1024 * 2);
  short* vTb    = (short*)alloc((size_t)NB * SS * 1024 * 2);
  short* rbf    = (short*)alloc((size_t)SS * 1024 * 2);
  int*   ki     = (int*)  alloc((size_t)NB * SS * 4);
  int2*  ranges = (int2*) alloc((size_t)NB * 64 * 8);
  float* ukT    = (float*)alloc((size_t)NB * NHD * SS * 4);
  float* vrT    = (float*)alloc((size_t)NHD * SS * 4);
  short* attn   = (short*)alloc((size_t)NB * TT * 1024 * 2);
  (void)ws_size; (void)in_sizes; (void)n_in; (void)out_size;

  // merged prep: pack + 5x transpose-cast + scan (one launch, R15)
  prep_kernel<<<NKVB + NTRB + NB, 256, 0, stream>>>(
      memory, x, rel, episode_idx, dones,
      Wq, Wk, Wv, Wr, Wout,
      kv_bf, rel_bf, WqT, WkT, WvT, WrT, WoT, ki, ranges);

  // fused projections, 64x64 tiles, R14 core + XCD-locality swizzle (R15)
  proj_gemm<<<dim3(1024, 1, 4), 256, 0, stream>>>(kv_bf, rel_bf,
                                                  WkT, WvT, WqT, WrT,
                                                  kbf, vTb, qbuf, rbf, ranges);

  // u·k / v·r column-bias tables
  bias_tables<<<(NB*NHD*SS + NHD*SS + 255)/256, 256, 0, stream>>>(kbf, rbf, u, v, ukT, vrT);

  // attention: one wave per 16-row q-group, load-batched + VGPR uncap (R16)
  attn_kernel<<<2048, 64, 0, stream>>>(qbuf, rbf, kbf, vTb, ki, ukT, vrT, ranges, attn);

  // output projection (XCD-locality swizzle)
  out_gemm<<<512, 256, 0, stream>>>(attn, WoT, b_out, out);
}